// Round 6
// baseline (527.107 us; speedup 1.0000x reference)
//
#include <hip/hip_runtime.h>
#include <hip/hip_fp16.h>
#include <math.h>

typedef _Float16 half8  __attribute__((ext_vector_type(8)));
typedef _Float16 half4v __attribute__((ext_vector_type(4)));
typedef float    floatx4 __attribute__((ext_vector_type(4)));

#define NB   4
#define LL   8192
#define FF   1024
#define HH   16
#define DD   64
#define MTOT 32768
#define KK   1024
#define NN   1024
#define ZSCALE 65536.0f

__device__ __forceinline__ void gload_lds16(const void* g, void* l) {
  __builtin_amdgcn_global_load_lds(
      (const __attribute__((address_space(1))) void*)g,
      (__attribute__((address_space(3))) void*)l, 16, 0, 0);
}

__device__ __forceinline__ float phi_act(float x) {
  return x > 0.f ? x + 1.f : __expf(x);
}

// ---------- elementwise f32 -> f16 ----------
__global__ void k_cvt(const float* __restrict__ src, _Float16* __restrict__ dst, int n4) {
  int stride = gridDim.x * blockDim.x;
  for (int i = blockIdx.x * blockDim.x + threadIdx.x; i < n4; i += stride) {
    float4 v = reinterpret_cast<const float4*>(src)[i];
    half4v h;
    h[0] = (_Float16)v.x; h[1] = (_Float16)v.y; h[2] = (_Float16)v.z; h[3] = (_Float16)v.w;
    reinterpret_cast<half4v*>(dst)[i] = h;
  }
}

// ---------- transpose+convert three 1024x1024 weights: W[f][n] -> WT16[n][f] ----------
__global__ void k_cvt_t(const float* __restrict__ W0, const float* __restrict__ W1,
                        const float* __restrict__ W2,
                        _Float16* __restrict__ T0, _Float16* __restrict__ T1,
                        _Float16* __restrict__ T2) {
  __shared__ float tile[32][33];
  int bid = blockIdx.x;
  int w = bid >> 10, rem = bid & 1023;
  int ti = rem >> 5, tj = rem & 31;
  const float* src = (w == 0) ? W0 : (w == 1) ? W1 : W2;
  _Float16*    dst = (w == 0) ? T0 : (w == 1) ? T1 : T2;
  int t = threadIdx.x;
  int r = t >> 3, c4 = (t & 7) << 2;
  float4 v = *reinterpret_cast<const float4*>(&src[(size_t)(ti * 32 + r) * FF + tj * 32 + c4]);
  tile[r][c4 + 0] = v.x; tile[r][c4 + 1] = v.y; tile[r][c4 + 2] = v.z; tile[r][c4 + 3] = v.w;
  __syncthreads();
  half4v h;
  h[0] = (_Float16)tile[c4 + 0][r];
  h[1] = (_Float16)tile[c4 + 1][r];
  h[2] = (_Float16)tile[c4 + 2][r];
  h[3] = (_Float16)tile[c4 + 3][r];
  *reinterpret_cast<half4v*>(&dst[(size_t)(tj * 32 + r) * FF + ti * 32 + c4]) = h;
}

// ============ 256x256-tile quadrant-schedule GEMM (BK=64, 8 waves 2x4) ============
// A[M,1024] f16 row-major, BT[N,1024] f16 row-major.
// LDS: [2 buf][A-h0, A-h1, B-h0, B-h1] planes of 16 KB = 128 KiB.
//   A-half h holds rows {r : bit6(r)==h} (MH-quadrant interleave), plane row
//   rp = (r>>7)*64 + (r&63);  B-half h holds rows {r : bit5(r)==h} (NH
//   interleave), rp = (r>>6)*32 + (r&31).  Plane = [128 rp][64 k] f16.
// Swizzle (involution, row-constant): byte ^= ((b>>9)&1)<<5 | ((b>>10)&1)<<6
//   -> frag reads spread 8 accesses/bank (even) for A and B patterns.
// Phases per K-tile: (MH,NH) = (0,0)(0,1)(1,0)(1,1); each = one C-quadrant
//   x full K=64 (16 MFMA).  Reads: ph0 8A+4B0, ph1 4B1, ph2 8A, ph3 0
//   (bA reused across NH, bB across MH).  Two barriers per phase (WAR safety
//   for restaging).  Stages (tile t): ph0->t+1 B-h1, ph1->t+1 A-h1,
//   ph2->t+2 A-h0 (self buf), ph3->t+2 B-h0 (self).  ONE vmcnt(4) per K-tile
//   at ph3 covers all of tile t+1's needs (derivation in journal; tail stages
//   clamped, never skipped, so counts stay valid).

template<int MATB, int HALF>
__device__ __forceinline__ void stage_half(const _Float16* __restrict__ G, int row0,
                                           int col0, _Float16* plane, int tid) {
  #pragma unroll
  for (int is = 0; is < 2; ++is) {
    int lin = is * 8192 + tid * 16;                 // linear dest byte in plane
    int swz = lin ^ ((((lin >> 9) & 1) << 5) | (((lin >> 10) & 1) << 6));
    int rp = swz >> 7;                              // plane row (= lin>>7)
    int kb = swz & 127;                             // swizzled k-byte
    int row;
    if constexpr (MATB) row = (rp >> 5) * 64 + HALF * 32 + (rp & 31);
    else                row = (rp >> 6) * 128 + HALF * 64 + (rp & 63);
    gload_lds16(G + (size_t)(row0 + row) * 1024 + col0 + (kb >> 1),
                (char*)plane + lin);
  }
}

__device__ __forceinline__ half8 frag_read(const _Float16* plane, int rp, int kk, int lh) {
  int byte = rp * 128 + kk * 64 + lh * 16;
  byte ^= (((byte >> 9) & 1) << 5) | (((byte >> 10) & 1) << 6);
  return *(const half8*)((const char*)plane + byte);
}

template<int MH, int NH>
__device__ __forceinline__ void qreads(const _Float16* sm, int buf,
                                       half8 (&bA)[8], half8 (&bB)[2][4],
                                       int wr, int wc, int lr, int lh) {
  if constexpr (NH == 0) {
    const _Float16* Ap = sm + buf * 32768 + MH * 8192;
    #pragma unroll
    for (int m = 0; m < 4; ++m)
      #pragma unroll
      for (int kk = 0; kk < 2; ++kk)
        bA[m * 2 + kk] = frag_read(Ap, wr * 64 + m * 16 + lr, kk, lh);
  }
  if constexpr (MH == 0) {
    const _Float16* Bp = sm + buf * 32768 + 16384 + NH * 8192;
    #pragma unroll
    for (int n = 0; n < 2; ++n)
      #pragma unroll
      for (int kk = 0; kk < 2; ++kk)
        bB[NH][n * 2 + kk] = frag_read(Bp, wc * 32 + n * 16 + lr, kk, lh);
  }
}

template<int MH, int NH, bool VM4>
__device__ __forceinline__ void qmfma(half8 (&bA)[8], half8 (&bB)[2][4],
                                      floatx4 (&acc)[8][4]) {
  if constexpr (VM4) {
    asm volatile("s_waitcnt vmcnt(4)" ::: "memory");
  }
  __builtin_amdgcn_s_barrier();
  asm volatile("s_waitcnt lgkmcnt(0)" ::: "memory");
  __builtin_amdgcn_sched_barrier(0);           // rule #18: pin MFMA after lgkm0
  __builtin_amdgcn_s_setprio(1);
  #pragma unroll
  for (int m = 0; m < 4; ++m)
    #pragma unroll
    for (int n = 0; n < 2; ++n)
      #pragma unroll
      for (int kk = 0; kk < 2; ++kk)
        acc[MH * 4 + m][NH * 2 + n] = __builtin_amdgcn_mfma_f32_16x16x32_f16(
            bA[m * 2 + kk], bB[NH][n * 2 + kk], acc[MH * 4 + m][NH * 2 + n], 0, 0, 0);
  __builtin_amdgcn_s_setprio(0);
  __builtin_amdgcn_s_barrier();
}

template<int TBUF>
__device__ __forceinline__ void do_tile(int t, const _Float16* __restrict__ Ab,
                                        const _Float16* __restrict__ Bb,
                                        int i0, int j0, _Float16* sm, int tid,
                                        half8 (&bA)[8], half8 (&bB)[2][4],
                                        floatx4 (&acc)[8][4],
                                        int wr, int wc, int lr, int lh) {
  _Float16* self  = sm + TBUF * 32768;
  _Float16* other = sm + (TBUF ^ 1) * 32768;
  const int c1 = ((t + 1 < 16) ? (t + 1) : 15) * 64;   // clamp: keep vmcnt counts uniform
  const int c2 = ((t + 2 < 16) ? (t + 2) : 15) * 64;
  // ph0 (MH0,NH0)
  qreads<0, 0>(sm, TBUF, bA, bB, wr, wc, lr, lh);
  stage_half<1, 1>(Bb, j0, c1, other + 24576, tid);    // t+1 B-h1
  qmfma<0, 0, false>(bA, bB, acc);
  // ph1 (MH0,NH1)
  qreads<0, 1>(sm, TBUF, bA, bB, wr, wc, lr, lh);
  stage_half<0, 1>(Ab, i0, c1, other + 8192, tid);     // t+1 A-h1
  qmfma<0, 1, false>(bA, bB, acc);
  // ph2 (MH1,NH0)
  qreads<1, 0>(sm, TBUF, bA, bB, wr, wc, lr, lh);
  stage_half<0, 0>(Ab, i0, c2, self + 0, tid);         // t+2 A-h0 (self buf; WAR-safe: A-h0 last read ph0)
  qmfma<1, 0, false>(bA, bB, acc);
  // ph3 (MH1,NH1) — no reads
  stage_half<1, 0>(Bb, j0, c2, self + 16384, tid);     // t+2 B-h0 (self; last read ph0)
  qmfma<1, 1, true>(bA, bB, acc);                      // single vmcnt(4) per K-tile
}

// MODE 0: f16 C[row*1024+col] (opt PHI)   MODE 1: f16 transposed CT[b][1024][8192]
// MODE 2: f32 C*outScale, BT indexed per-batch
template<int MODE, bool PHI>
__global__ __launch_bounds__(512, 2)
void k_gemm(const _Float16* __restrict__ A, const _Float16* __restrict__ BT,
            void* __restrict__ Cptr, float outScale) {
  __shared__ __align__(16) _Float16 smem[65536];   // 128 KiB
  const int tid  = threadIdx.x;
  const int lane = tid & 63;
  const int wid  = tid >> 6;
  const int wr = wid >> 2, wc = wid & 3;
  const int lr = lane & 15, lh = lane >> 4;

  // XCD-chunked block swizzle: 512 blocks, 64 contiguous tiles per XCD
  const int tile = (blockIdx.x & 7) * 64 + (blockIdx.x >> 3);
  const int tm = tile >> 2, tn = tile & 3;
  const int i0 = tm * 256, j0 = tn * 256;

  const _Float16* Ab = A;
  const _Float16* Bb = (MODE == 2) ? BT + ((size_t)(i0 >> 13)) * ((size_t)NN * KK) : BT;

  floatx4 acc[8][4];
  #pragma unroll
  for (int m = 0; m < 8; ++m)
    #pragma unroll
    for (int n = 0; n < 4; ++n)
      #pragma unroll
      for (int r = 0; r < 4; ++r) acc[m][n][r] = 0.f;

  _Float16* sm = (_Float16*)smem;
  half8 bA[8];
  half8 bB[2][4];

  // prologue: t0's 4 planes + t1's A-h0,B-h0 (6 stages = 12 loads); vmcnt(4)
  // completes t0's 4, leaves t1's 2 = steady invariant {t-1 ph2, t-1 ph3}.
  stage_half<0, 0>(Ab, i0, 0,  sm + 0,             tid);
  stage_half<1, 0>(Bb, j0, 0,  sm + 16384,         tid);
  stage_half<1, 1>(Bb, j0, 0,  sm + 24576,         tid);
  stage_half<0, 1>(Ab, i0, 0,  sm + 8192,          tid);
  stage_half<0, 0>(Ab, i0, 64, sm + 32768 + 0,     tid);
  stage_half<1, 0>(Bb, j0, 64, sm + 32768 + 16384, tid);
  asm volatile("s_waitcnt vmcnt(4)" ::: "memory");
  __builtin_amdgcn_s_barrier();

  #pragma unroll 1
  for (int tt = 0; tt < 8; ++tt) {
    do_tile<0>(2 * tt,     Ab, Bb, i0, j0, sm, tid, bA, bB, acc, wr, wc, lr, lh);
    do_tile<1>(2 * tt + 1, Ab, Bb, i0, j0, sm, tid, bA, bB, acc, wr, wc, lr, lh);
  }

  asm volatile("s_waitcnt vmcnt(0)" ::: "memory");
  __builtin_amdgcn_s_barrier();

  if constexpr (MODE == 0) {
    _Float16* C = (_Float16*)Cptr;
    #pragma unroll
    for (int m = 0; m < 8; ++m) {
      int row = i0 + wr * 128 + m * 16 + lh * 4;
      #pragma unroll
      for (int n = 0; n < 4; ++n) {
        int col = j0 + wc * 64 + n * 16 + lr;
        #pragma unroll
        for (int r = 0; r < 4; ++r) {
          float v = acc[m][n][r];
          if constexpr (PHI) v = phi_act(v);
          C[(size_t)(row + r) * NN + col] = (_Float16)v;
        }
      }
    }
  } else if constexpr (MODE == 2) {
    float* C = (float*)Cptr;
    #pragma unroll
    for (int m = 0; m < 8; ++m) {
      int row = i0 + wr * 128 + m * 16 + lh * 4;
      #pragma unroll
      for (int n = 0; n < 4; ++n) {
        int col = j0 + wc * 64 + n * 16 + lr;
        #pragma unroll
        for (int r = 0; r < 4; ++r)
          C[(size_t)(row + r) * NN + col] = acc[m][n][r] * outScale;
      }
    }
  } else {
    // transposed store via LDS (reuse smem = 256n x 256l f16 = 128KB exactly)
    #pragma unroll
    for (int m = 0; m < 8; ++m) {
      int l0l = wr * 128 + m * 16 + lh * 4;
      #pragma unroll
      for (int n = 0; n < 4; ++n) {
        int n_loc = wc * 64 + n * 16 + lr;
        int byte = (n_loc * 512 + l0l * 2) ^ ((n_loc & 7) << 4);
        half4v h;
        #pragma unroll
        for (int r = 0; r < 4; ++r) {
          float v = acc[m][n][r];
          if constexpr (PHI) v = phi_act(v);
          h[r] = (_Float16)v;
        }
        *(half4v*)((char*)sm + byte) = h;
      }
    }
    __syncthreads();
    _Float16* C = (_Float16*)Cptr;
    const int bb = i0 >> 13;
    const int l0 = i0 & 8191;
    #pragma unroll 1
    for (int pass = 0; pass < 16; ++pass) {
      int n_loc = pass * 16 + (tid >> 5);
      int lo = (tid & 31) * 16;                     // byte offset within 512B l-row
      int byte = (n_loc * 512 + lo) ^ ((n_loc & 7) << 4);
      half8 v = *(const half8*)((char*)sm + byte);
      *(half8*)&C[((size_t)bb * 1024 + j0 + n_loc) * LL + l0 + (lo >> 1)] = v;
    }
  }
}

// ---------- ksum[b,h,d] = sum_l phi(k): row sums of kpT ----------
__global__ void k_ksum(const _Float16* __restrict__ kpT, float* __restrict__ ksum) {
  int w = threadIdx.x >> 6, lane = threadIdx.x & 63;
  int row = blockIdx.x * 4 + w;
  const _Float16* p = kpT + (size_t)row * LL;
  float s = 0.f;
  for (int j = 0; j < 16; ++j) {
    half8 v = *(const half8*)&p[j * 512 + lane * 8];
    #pragma unroll
    for (int e = 0; e < 8; ++e) s += (float)v[e];
  }
  #pragma unroll
  for (int off = 1; off < 64; off <<= 1) s += __shfl_xor(s, off);
  if (lane == 0) ksum[row] = s;
}

// ---------- kv partials: per (b,h,chunk) wave computes 64x64 = kp^T(chunk) * v(chunk) ----------
__global__ __launch_bounds__(64)
void k_stageB(const _Float16* __restrict__ kpT, const _Float16* __restrict__ vT,
              float* __restrict__ kvpart) {
  __shared__ _Float16 Ak[64 * 72];
  __shared__ _Float16 Bv[64 * 72];
  const int bid = blockIdx.x;
  const int bh = bid >> 4, cc = bid & 15;
  const int lane = threadIdx.x;
  const int lr = lane & 15, lh = lane >> 4;
  const _Float16* Ab = kpT + (size_t)bh * 64 * LL + cc * 512;
  const _Float16* Bb = vT  + (size_t)bh * 64 * LL + cc * 512;

  floatx4 acc[4][4];
  #pragma unroll
  for (int m = 0; m < 4; ++m)
    #pragma unroll
    for (int n = 0; n < 4; ++n)
      #pragma unroll
      for (int r = 0; r < 4; ++r) acc[m][n][r] = 0.f;

  for (int kt = 0; kt < 512; kt += 64) {
    __syncthreads();
    #pragma unroll
    for (int j = 0; j < 8; ++j) {
      int chunk = lane + 64 * j;
      int rr = chunk >> 3;
      int off = (chunk & 7) * 8;
      *(half8*)&Ak[rr * 72 + off] = *(const half8*)&Ab[(size_t)rr * LL + kt + off];
      *(half8*)&Bv[rr * 72 + off] = *(const half8*)&Bb[(size_t)rr * LL + kt + off];
    }
    __syncthreads();
    #pragma unroll
    for (int ks = 0; ks < 2; ++ks) {
      half8 af[4], bf[4];
      #pragma unroll
      for (int m = 0; m < 4; ++m) af[m] = *(const half8*)&Ak[(m * 16 + lr) * 72 + ks * 32 + lh * 8];
      #pragma unroll
      for (int n = 0; n < 4; ++n) bf[n] = *(const half8*)&Bv[(n * 16 + lr) * 72 + ks * 32 + lh * 8];
      #pragma unroll
      for (int m = 0; m < 4; ++m)
        #pragma unroll
        for (int n = 0; n < 4; ++n)
          acc[m][n] = __builtin_amdgcn_mfma_f32_16x16x32_f16(af[m], bf[n], acc[m][n], 0, 0, 0);
    }
  }
  float* op = kvpart + (size_t)bid * 4096;
  #pragma unroll
  for (int m = 0; m < 4; ++m)
    #pragma unroll
    for (int n = 0; n < 4; ++n)
      #pragma unroll
      for (int r = 0; r < 4; ++r)
        op[(m * 16 + lh * 4 + r) * 64 + n * 16 + lr] = acc[m][n][r];
}

// ---------- reduce kv partials over 16 chunks ----------
__global__ void k_reduce_kv(const float* __restrict__ kvpart, float* __restrict__ kv) {
  int gid = blockIdx.x * 256 + threadIdx.x;
  int bh = gid >> 12, i = gid & 4095;
  float s = 0.f;
  for (int c = 0; c < 16; ++c) s += kvpart[((size_t)bh * 16 + c) * 4096 + i];
  kv[gid] = s;
}

// ---------- z = ZSCALE / (phi(q).ksum + eps); qp *= z in place ----------
__global__ void k_zscale(_Float16* __restrict__ qp, const float* __restrict__ ksum) {
  int w = threadIdx.x >> 6, lane = threadIdx.x & 63;
  int row = blockIdx.x * 4 + w;
  int b = row >> 13;
  int h = lane >> 2;
  _Float16* p = qp + (size_t)row * 1024 + lane * 16;
  half8 v0 = *(half8*)&p[0];
  half8 v1 = *(half8*)&p[8];
  const float* ks = ksum + ((size_t)b * 16 + h) * 64 + (lane & 3) * 16;
  float dot = 0.f;
  #pragma unroll
  for (int e = 0; e < 8; ++e) dot += (float)v0[e] * ks[e];
  #pragma unroll
  for (int e = 0; e < 8; ++e) dot += (float)v1[e] * ks[8 + e];
  dot += __shfl_xor(dot, 1);
  dot += __shfl_xor(dot, 2);
  float zf = ZSCALE / (dot + 1e-6f);
  #pragma unroll
  for (int e = 0; e < 8; ++e) v0[e] = (_Float16)((float)v0[e] * zf);
  #pragma unroll
  for (int e = 0; e < 8; ++e) v1[e] = (_Float16)((float)v1[e] * zf);
  *(half8*)&p[0] = v0;
  *(half8*)&p[8] = v1;
}

// ---------- MT[b][f][h*64+d] = sum_e kv[b,h,d,e] * Wo[h,e,f] ----------
__global__ __launch_bounds__(256)
void k_mker(const float* __restrict__ kv, const _Float16* __restrict__ Wo16,
            _Float16* __restrict__ MT) {
  __shared__ float kvs[4096];
  int bid = blockIdx.x;
  int fc = bid & 3, h = (bid >> 2) & 15, b = bid >> 6;
  const float* kvp = kv + ((size_t)b * 16 + h) * 4096;
  for (int i = threadIdx.x; i < 4096; i += 256) kvs[i] = kvp[i];
  __syncthreads();
  int f = fc * 256 + threadIdx.x;
  float acc[64];
  #pragma unroll
  for (int d = 0; d < 64; ++d) acc[d] = 0.f;
  for (int e = 0; e < 64; ++e) {
    float wv = (float)Wo16[(size_t)(h * 64 + e) * 1024 + f];
    #pragma unroll
    for (int d = 0; d < 64; ++d) acc[d] = fmaf(kvs[d * 64 + e], wv, acc[d]);
  }
  _Float16* op = MT + ((size_t)b * 1024 + f) * 1024 + h * 64;
  #pragma unroll
  for (int g = 0; g < 8; ++g) {
    half8 o;
    #pragma unroll
    for (int j = 0; j < 8; ++j) o[j] = (_Float16)acc[g * 8 + j];
    *(half8*)&op[g * 8] = o;
  }
}

extern "C" void kernel_launch(void* const* d_in, const int* in_sizes, int n_in,
                              void* d_out, int out_size, void* d_ws, size_t ws_size,
                              hipStream_t stream) {
  (void)in_sizes; (void)n_in; (void)out_size; (void)ws_size;
  const float* xq  = (const float*)d_in[0];
  const float* xkv = (const float*)d_in[1];
  const float* Wq  = (const float*)d_in[2];
  const float* Wk  = (const float*)d_in[3];
  const float* Wv  = (const float*)d_in[4];
  const float* Wo  = (const float*)d_in[5];

  char* ws = (char*)d_ws;
  _Float16* qp16 = (_Float16*)(ws + 0);           // [32768][1024]
  _Float16* kpT  = (_Float16*)(ws + 67108864);    // [4][1024][8192]
  _Float16* vT   = (_Float16*)(ws + 134217728);   // [4][1024][8192]
  _Float16* WqT  = (_Float16*)(ws + 201326592);
  _Float16* WkT  = (_Float16*)(ws + 203423744);
  _Float16* WvT  = (_Float16*)(ws + 205520896);
  _Float16* Wo16 = (_Float16*)(ws + 207618048);
  float*    ksum = (float*)(ws + 209715200);
  float*    kv   = (float*)(ws + 209731584);
  float*    kvpart = (float*)(ws + 210780160);
  _Float16* MT   = (_Float16*)(ws + 227557376);   // [4][1024][1024]

  _Float16* Xq16  = (_Float16*)d_out;
  _Float16* Xkv16 = Xq16 + 33554432;

  k_cvt<<<2048, 256, 0, stream>>>(xq,  Xq16,  8388608);
  k_cvt<<<2048, 256, 0, stream>>>(xkv, Xkv16, 8388608);
  k_cvt<<<512,  256, 0, stream>>>(Wo,  Wo16,  262144);
  k_cvt_t<<<3072, 256, 0, stream>>>(Wq, Wk, Wv, WqT, WkT, WvT);

  // projections: 256x256 tiles -> 128 x 4 = 512 blocks of 512 threads
  k_gemm<0, true ><<<512, 512, 0, stream>>>(Xq16,  WqT, qp16, 1.0f);
  k_gemm<1, true ><<<512, 512, 0, stream>>>(Xkv16, WkT, kpT,  1.0f);
  k_gemm<1, false><<<512, 512, 0, stream>>>(Xkv16, WvT, vT,   1.0f);

  k_ksum<<<1024, 256, 0, stream>>>(kpT, ksum);
  k_stageB<<<1024, 64, 0, stream>>>(kpT, vT, kvpart);
  k_reduce_kv<<<1024, 256, 0, stream>>>(kvpart, kv);

  k_zscale<<<8192, 256, 0, stream>>>(qp16, ksum);

  k_mker<<<256, 256, 0, stream>>>(kv, Wo16, MT);
  k_gemm<2, false><<<512, 512, 0, stream>>>(qp16, MT, d_out, 1.0f / ZSCALE);
}

// Round 8
// 515.944 us; speedup vs baseline: 1.0216x; 1.0216x over previous
//
#include <hip/hip_runtime.h>
#include <hip/hip_fp16.h>
#include <math.h>

typedef _Float16 half8  __attribute__((ext_vector_type(8)));
typedef _Float16 half4v __attribute__((ext_vector_type(4)));
typedef float    floatx4 __attribute__((ext_vector_type(4)));

#define NB   4
#define LL   8192
#define FF   1024
#define HH   16
#define DD   64
#define MTOT 32768
#define KK   1024
#define NN   1024
#define ZSCALE 65536.0f

__device__ __forceinline__ void gload_lds16(const void* g, void* l) {
  __builtin_amdgcn_global_load_lds(
      (const __attribute__((address_space(1))) void*)g,
      (__attribute__((address_space(3))) void*)l, 16, 0, 0);
}

__device__ __forceinline__ float phi_act(float x) {
  return x > 0.f ? x + 1.f : __expf(x);
}

// ---------- elementwise f32 -> f16 ----------
__global__ void k_cvt(const float* __restrict__ src, _Float16* __restrict__ dst, int n4) {
  int stride = gridDim.x * blockDim.x;
  for (int i = blockIdx.x * blockDim.x + threadIdx.x; i < n4; i += stride) {
    float4 v = reinterpret_cast<const float4*>(src)[i];
    half4v h;
    h[0] = (_Float16)v.x; h[1] = (_Float16)v.y; h[2] = (_Float16)v.z; h[3] = (_Float16)v.w;
    reinterpret_cast<half4v*>(dst)[i] = h;
  }
}

// ---------- transpose+convert three 1024x1024 weights: W[f][n] -> WT16[n][f] ----------
__global__ void k_cvt_t(const float* __restrict__ W0, const float* __restrict__ W1,
                        const float* __restrict__ W2,
                        _Float16* __restrict__ T0, _Float16* __restrict__ T1,
                        _Float16* __restrict__ T2) {
  __shared__ float tile[32][33];
  int bid = blockIdx.x;
  int w = bid >> 10, rem = bid & 1023;
  int ti = rem >> 5, tj = rem & 31;
  const float* src = (w == 0) ? W0 : (w == 1) ? W1 : W2;
  _Float16*    dst = (w == 0) ? T0 : (w == 1) ? T1 : T2;
  int t = threadIdx.x;
  int r = t >> 3, c4 = (t & 7) << 2;
  float4 v = *reinterpret_cast<const float4*>(&src[(size_t)(ti * 32 + r) * FF + tj * 32 + c4]);
  tile[r][c4 + 0] = v.x; tile[r][c4 + 1] = v.y; tile[r][c4 + 2] = v.z; tile[r][c4 + 3] = v.w;
  __syncthreads();
  half4v h;
  h[0] = (_Float16)tile[c4 + 0][r];
  h[1] = (_Float16)tile[c4 + 1][r];
  h[2] = (_Float16)tile[c4 + 2][r];
  h[3] = (_Float16)tile[c4 + 3][r];
  *reinterpret_cast<half4v*>(&dst[(size_t)(tj * 32 + r) * FF + ti * 32 + c4]) = h;
}

// ============ 256x256-tile quadrant-schedule GEMM (BK=64, 8 waves 2x4) ============
// A[M,1024] f16 row-major, BT[N,1024] f16 row-major.
// LDS: [2 buf][A-h0, A-h1, B-h0, B-h1] planes of 16 KB = 128 KiB.
//   A-half h holds rows {r : bit6(r)==h}, plane row rp = (r>>7)*64 + (r&63);
//   B-half h holds rows {r : bit5(r)==h}, rp = (r>>6)*32 + (r&31).
//   Plane = [128 rp][64 k] f16 (128 B row stride).
// Swizzle (involution, r7 FIX): byte ^= ((byte>>7)&7)<<4
//   -> slot = lh ^ (rp&7): 16 lanes -> 8 slots x 2 = 2-way (free, m136).
//   (r6's dual-XOR left slot depending only on rp bits 2-3 -> 4-way, 6.8M confl.)
// Phases per K-tile: (MH,NH) = (0,0)(0,1)(1,0)(1,1); each = one C-quadrant
//   x full K=64 (16 MFMA).  Reads: ph0 8A+4B, ph1 4B, ph2 8A, ph3 0.
//   Two barriers per phase.  Stages (tile t): ph0->t+1 B-h1, ph1->t+1 A-h1,
//   ph2->t+2 A-h0 (self buf), ph3->t+2 B-h0 (self).  ONE vmcnt(4) per K-tile
//   at ph3 covers all of tile t+1's needs; tail stages clamped, never skipped.

template<int MATB, int HALF>
__device__ __forceinline__ void stage_half(const _Float16* __restrict__ G, int row0,
                                           int col0, _Float16* plane, int tid) {
  #pragma unroll
  for (int is = 0; is < 2; ++is) {
    int lin = is * 8192 + tid * 16;                 // linear dest byte in plane
    int swz = lin ^ (((lin >> 7) & 7) << 4);        // inverse-swizzled source
    int rp = swz >> 7;                              // plane row (= lin>>7)
    int kb = swz & 127;                             // swizzled k-byte
    int row;
    if constexpr (MATB) row = (rp >> 5) * 64 + HALF * 32 + (rp & 31);
    else                row = (rp >> 6) * 128 + HALF * 64 + (rp & 63);
    gload_lds16(G + (size_t)(row0 + row) * 1024 + col0 + (kb >> 1),
                (char*)plane + lin);
  }
}

__device__ __forceinline__ half8 frag_read(const _Float16* plane, int rp, int kk, int lh) {
  int byte = rp * 128 + kk * 64 + lh * 16;
  byte ^= ((byte >> 7) & 7) << 4;
  return *(const half8*)((const char*)plane + byte);
}

template<int MH, int NH>
__device__ __forceinline__ void qreads(const _Float16* sm, int buf,
                                       half8 (&bA)[8], half8 (&bB)[2][4],
                                       int wr, int wc, int lr, int lh) {
  if constexpr (NH == 0) {
    const _Float16* Ap = sm + buf * 32768 + MH * 8192;
    #pragma unroll
    for (int m = 0; m < 4; ++m)
      #pragma unroll
      for (int kk = 0; kk < 2; ++kk)
        bA[m * 2 + kk] = frag_read(Ap, wr * 64 + m * 16 + lr, kk, lh);
  }
  if constexpr (MH == 0) {
    const _Float16* Bp = sm + buf * 32768 + 16384 + NH * 8192;
    #pragma unroll
    for (int n = 0; n < 2; ++n)
      #pragma unroll
      for (int kk = 0; kk < 2; ++kk)
        bB[NH][n * 2 + kk] = frag_read(Bp, wc * 32 + n * 16 + lr, kk, lh);
  }
}

template<int MH, int NH, bool VM4>
__device__ __forceinline__ void qmfma(half8 (&bA)[8], half8 (&bB)[2][4],
                                      floatx4 (&acc)[8][4]) {
  if constexpr (VM4) {
    asm volatile("s_waitcnt vmcnt(4)" ::: "memory");
  }
  __builtin_amdgcn_s_barrier();
  asm volatile("s_waitcnt lgkmcnt(0)" ::: "memory");
  __builtin_amdgcn_sched_barrier(0);           // rule #18: pin MFMA after lgkm0
  __builtin_amdgcn_s_setprio(1);
  #pragma unroll
  for (int m = 0; m < 4; ++m)
    #pragma unroll
    for (int n = 0; n < 2; ++n)
      #pragma unroll
      for (int kk = 0; kk < 2; ++kk)
        acc[MH * 4 + m][NH * 2 + n] = __builtin_amdgcn_mfma_f32_16x16x32_f16(
            bA[m * 2 + kk], bB[NH][n * 2 + kk], acc[MH * 4 + m][NH * 2 + n], 0, 0, 0);
  __builtin_amdgcn_s_setprio(0);
  __builtin_amdgcn_s_barrier();
}

template<int TBUF>
__device__ __forceinline__ void do_tile(int t, const _Float16* __restrict__ Ab,
                                        const _Float16* __restrict__ Bb,
                                        int i0, int j0, _Float16* sm, int tid,
                                        half8 (&bA)[8], half8 (&bB)[2][4],
                                        floatx4 (&acc)[8][4],
                                        int wr, int wc, int lr, int lh) {
  _Float16* self  = sm + TBUF * 32768;
  _Float16* other = sm + (TBUF ^ 1) * 32768;
  const int c1 = ((t + 1 < 16) ? (t + 1) : 15) * 64;   // clamp: keep vmcnt counts uniform
  const int c2 = ((t + 2 < 16) ? (t + 2) : 15) * 64;
  // ph0 (MH0,NH0)
  qreads<0, 0>(sm, TBUF, bA, bB, wr, wc, lr, lh);
  stage_half<1, 1>(Bb, j0, c1, other + 24576, tid);    // t+1 B-h1
  qmfma<0, 0, false>(bA, bB, acc);
  // ph1 (MH0,NH1)
  qreads<0, 1>(sm, TBUF, bA, bB, wr, wc, lr, lh);
  stage_half<0, 1>(Ab, i0, c1, other + 8192, tid);     // t+1 A-h1
  qmfma<0, 1, false>(bA, bB, acc);
  // ph2 (MH1,NH0)
  qreads<1, 0>(sm, TBUF, bA, bB, wr, wc, lr, lh);
  stage_half<0, 0>(Ab, i0, c2, self + 0, tid);         // t+2 A-h0 (self buf; WAR-safe)
  qmfma<1, 0, false>(bA, bB, acc);
  // ph3 (MH1,NH1) — no reads
  stage_half<1, 0>(Bb, j0, c2, self + 16384, tid);     // t+2 B-h0 (self)
  qmfma<1, 1, true>(bA, bB, acc);                      // single vmcnt(4) per K-tile
}

// MODE 0: f16 C[row*1024+col] (opt PHI)   MODE 1: f16 transposed CT[b][1024][8192]
// MODE 2: f32 C*outScale, BT indexed per-batch
template<int MODE, bool PHI>
__global__ __launch_bounds__(512, 2)
void k_gemm(const _Float16* __restrict__ A, const _Float16* __restrict__ BT,
            void* __restrict__ Cptr, float outScale) {
  __shared__ __align__(16) _Float16 smem[65536];   // 128 KiB
  const int tid  = threadIdx.x;
  const int lane = tid & 63;
  const int wid  = tid >> 6;
  const int wr = wid >> 2, wc = wid & 3;
  const int lr = lane & 15, lh = lane >> 4;

  // XCD-chunked block swizzle: 512 blocks, 64 contiguous tiles per XCD
  const int tile = (blockIdx.x & 7) * 64 + (blockIdx.x >> 3);
  const int tm = tile >> 2, tn = tile & 3;
  const int i0 = tm * 256, j0 = tn * 256;

  const _Float16* Ab = A;
  const _Float16* Bb = (MODE == 2) ? BT + ((size_t)(i0 >> 13)) * ((size_t)NN * KK) : BT;

  floatx4 acc[8][4];
  #pragma unroll
  for (int m = 0; m < 8; ++m)
    #pragma unroll
    for (int n = 0; n < 4; ++n)
      #pragma unroll
      for (int r = 0; r < 4; ++r) acc[m][n][r] = 0.f;

  _Float16* sm = (_Float16*)smem;
  half8 bA[8];
  half8 bB[2][4];

  // prologue: t0's 4 planes + t1's A-h0,B-h0 (6 stages = 12 loads); vmcnt(4)
  // completes t0's 4, leaves t1's 2 = steady invariant {t-1 ph2, t-1 ph3}.
  stage_half<0, 0>(Ab, i0, 0,  sm + 0,             tid);
  stage_half<1, 0>(Bb, j0, 0,  sm + 16384,         tid);
  stage_half<1, 1>(Bb, j0, 0,  sm + 24576,         tid);
  stage_half<0, 1>(Ab, i0, 0,  sm + 8192,          tid);
  stage_half<0, 0>(Ab, i0, 64, sm + 32768 + 0,     tid);
  stage_half<1, 0>(Bb, j0, 64, sm + 32768 + 16384, tid);
  asm volatile("s_waitcnt vmcnt(4)" ::: "memory");
  __builtin_amdgcn_s_barrier();

  #pragma unroll 1
  for (int tt = 0; tt < 8; ++tt) {
    do_tile<0>(2 * tt,     Ab, Bb, i0, j0, sm, tid, bA, bB, acc, wr, wc, lr, lh);
    do_tile<1>(2 * tt + 1, Ab, Bb, i0, j0, sm, tid, bA, bB, acc, wr, wc, lr, lh);
  }

  asm volatile("s_waitcnt vmcnt(0)" ::: "memory");
  __builtin_amdgcn_s_barrier();

  if constexpr (MODE == 0) {
    _Float16* C = (_Float16*)Cptr;
    #pragma unroll
    for (int m = 0; m < 8; ++m) {
      int row = i0 + wr * 128 + m * 16 + lh * 4;
      #pragma unroll
      for (int n = 0; n < 4; ++n) {
        int col = j0 + wc * 64 + n * 16 + lr;
        #pragma unroll
        for (int r = 0; r < 4; ++r) {
          float v = acc[m][n][r];
          if constexpr (PHI) v = phi_act(v);
          C[(size_t)(row + r) * NN + col] = (_Float16)v;
        }
      }
    }
  } else if constexpr (MODE == 2) {
    float* C = (float*)Cptr;
    #pragma unroll
    for (int m = 0; m < 8; ++m) {
      int row = i0 + wr * 128 + m * 16 + lh * 4;
      #pragma unroll
      for (int n = 0; n < 4; ++n) {
        int col = j0 + wc * 64 + n * 16 + lr;
        #pragma unroll
        for (int r = 0; r < 4; ++r)
          C[(size_t)(row + r) * NN + col] = acc[m][n][r] * outScale;
      }
    }
  } else {
    // transposed store via LDS (reuse smem = 256n x 256l f16 = 128KB exactly)
    #pragma unroll
    for (int m = 0; m < 8; ++m) {
      int l0l = wr * 128 + m * 16 + lh * 4;
      #pragma unroll
      for (int n = 0; n < 4; ++n) {
        int n_loc = wc * 64 + n * 16 + lr;
        int byte = (n_loc * 512 + l0l * 2) ^ ((n_loc & 7) << 4);
        half4v h;
        #pragma unroll
        for (int r = 0; r < 4; ++r) {
          float v = acc[m][n][r];
          if constexpr (PHI) v = phi_act(v);
          h[r] = (_Float16)v;
        }
        *(half4v*)((char*)sm + byte) = h;
      }
    }
    __syncthreads();
    _Float16* C = (_Float16*)Cptr;
    const int bb = i0 >> 13;
    const int l0 = i0 & 8191;
    #pragma unroll 1
    for (int pass = 0; pass < 16; ++pass) {
      int n_loc = pass * 16 + (tid >> 5);
      int lo = (tid & 31) * 16;                     // byte offset within 512B l-row
      int byte = (n_loc * 512 + lo) ^ ((n_loc & 7) << 4);
      half8 v = *(const half8*)((char*)sm + byte);
      *(half8*)&C[((size_t)bb * 1024 + j0 + n_loc) * LL + l0 + (lo >> 1)] = v;
    }
  }
}

// ---------- ksum[b,h,d] = sum_l phi(k): row sums of kpT ----------
__global__ void k_ksum(const _Float16* __restrict__ kpT, float* __restrict__ ksum) {
  int w = threadIdx.x >> 6, lane = threadIdx.x & 63;
  int row = blockIdx.x * 4 + w;
  const _Float16* p = kpT + (size_t)row * LL;
  float s = 0.f;
  for (int j = 0; j < 16; ++j) {
    half8 v = *(const half8*)&p[j * 512 + lane * 8];
    #pragma unroll
    for (int e = 0; e < 8; ++e) s += (float)v[e];
  }
  #pragma unroll
  for (int off = 1; off < 64; off <<= 1) s += __shfl_xor(s, off);
  if (lane == 0) ksum[row] = s;
}

// ---------- kv partials: per (b,h,chunk) wave computes 64x64 = kp^T(chunk) * v(chunk) ----------
__global__ __launch_bounds__(64)
void k_stageB(const _Float16* __restrict__ kpT, const _Float16* __restrict__ vT,
              float* __restrict__ kvpart) {
  __shared__ _Float16 Ak[64 * 72];
  __shared__ _Float16 Bv[64 * 72];
  const int bid = blockIdx.x;
  const int bh = bid >> 4, cc = bid & 15;
  const int lane = threadIdx.x;
  const int lr = lane & 15, lh = lane >> 4;
  const _Float16* Ab = kpT + (size_t)bh * 64 * LL + cc * 512;
  const _Float16* Bb = vT  + (size_t)bh * 64 * LL + cc * 512;

  floatx4 acc[4][4];
  #pragma unroll
  for (int m = 0; m < 4; ++m)
    #pragma unroll
    for (int n = 0; n < 4; ++n)
      #pragma unroll
      for (int r = 0; r < 4; ++r) acc[m][n][r] = 0.f;

  for (int kt = 0; kt < 512; kt += 64) {
    __syncthreads();
    #pragma unroll
    for (int j = 0; j < 8; ++j) {
      int chunk = lane + 64 * j;
      int rr = chunk >> 3;
      int off = (chunk & 7) * 8;
      *(half8*)&Ak[rr * 72 + off] = *(const half8*)&Ab[(size_t)rr * LL + kt + off];
      *(half8*)&Bv[rr * 72 + off] = *(const half8*)&Bb[(size_t)rr * LL + kt + off];
    }
    __syncthreads();
    #pragma unroll
    for (int ks = 0; ks < 2; ++ks) {
      half8 af[4], bf[4];
      #pragma unroll
      for (int m = 0; m < 4; ++m) af[m] = *(const half8*)&Ak[(m * 16 + lr) * 72 + ks * 32 + lh * 8];
      #pragma unroll
      for (int n = 0; n < 4; ++n) bf[n] = *(const half8*)&Bv[(n * 16 + lr) * 72 + ks * 32 + lh * 8];
      #pragma unroll
      for (int m = 0; m < 4; ++m)
        #pragma unroll
        for (int n = 0; n < 4; ++n)
          acc[m][n] = __builtin_amdgcn_mfma_f32_16x16x32_f16(af[m], bf[n], acc[m][n], 0, 0, 0);
    }
  }
  float* op = kvpart + (size_t)bid * 4096;
  #pragma unroll
  for (int m = 0; m < 4; ++m)
    #pragma unroll
    for (int n = 0; n < 4; ++n)
      #pragma unroll
      for (int r = 0; r < 4; ++r)
        op[(m * 16 + lh * 4 + r) * 64 + n * 16 + lr] = acc[m][n][r];
}

// ---------- reduce kv partials over 16 chunks ----------
__global__ void k_reduce_kv(const float* __restrict__ kvpart, float* __restrict__ kv) {
  int gid = blockIdx.x * 256 + threadIdx.x;
  int bh = gid >> 12, i = gid & 4095;
  float s = 0.f;
  for (int c = 0; c < 16; ++c) s += kvpart[((size_t)bh * 16 + c) * 4096 + i];
  kv[gid] = s;
}

// ---------- z = ZSCALE / (phi(q).ksum + eps); qp *= z in place ----------
__global__ void k_zscale(_Float16* __restrict__ qp, const float* __restrict__ ksum) {
  int w = threadIdx.x >> 6, lane = threadIdx.x & 63;
  int row = blockIdx.x * 4 + w;
  int b = row >> 13;
  int h = lane >> 2;
  _Float16* p = qp + (size_t)row * 1024 + lane * 16;
  half8 v0 = *(half8*)&p[0];
  half8 v1 = *(half8*)&p[8];
  const float* ks = ksum + ((size_t)b * 16 + h) * 64 + (lane & 3) * 16;
  float dot = 0.f;
  #pragma unroll
  for (int e = 0; e < 8; ++e) dot += (float)v0[e] * ks[e];
  #pragma unroll
  for (int e = 0; e < 8; ++e) dot += (float)v1[e] * ks[8 + e];
  dot += __shfl_xor(dot, 1);
  dot += __shfl_xor(dot, 2);
  float zf = ZSCALE / (dot + 1e-6f);
  #pragma unroll
  for (int e = 0; e < 8; ++e) v0[e] = (_Float16)((float)v0[e] * zf);
  #pragma unroll
  for (int e = 0; e < 8; ++e) v1[e] = (_Float16)((float)v1[e] * zf);
  *(half8*)&p[0] = v0;
  *(half8*)&p[8] = v1;
}

// ---------- MT[b][f][h*64+d] = sum_e kv[b,h,d,e] * Wo[h,e,f] ----------
__global__ __launch_bounds__(256)
void k_mker(const float* __restrict__ kv, const _Float16* __restrict__ Wo16,
            _Float16* __restrict__ MT) {
  __shared__ float kvs[4096];
  int bid = blockIdx.x;
  int fc = bid & 3, h = (bid >> 2) & 15, b = bid >> 6;
  const float* kvp = kv + ((size_t)b * 16 + h) * 4096;
  for (int i = threadIdx.x; i < 4096; i += 256) kvs[i] = kvp[i];
  __syncthreads();
  int f = fc * 256 + threadIdx.x;
  float acc[64];
  #pragma unroll
  for (int d = 0; d < 64; ++d) acc[d] = 0.f;
  for (int e = 0; e < 64; ++e) {
    float wv = (float)Wo16[(size_t)(h * 64 + e) * 1024 + f];
    #pragma unroll
    for (int d = 0; d < 64; ++d) acc[d] = fmaf(kvs[d * 64 + e], wv, acc[d]);
  }
  _Float16* op = MT + ((size_t)b * 1024 + f) * 1024 + h * 64;
  #pragma unroll
  for (int g = 0; g < 8; ++g) {
    half8 o;
    #pragma unroll
    for (int j = 0; j < 8; ++j) o[j] = (_Float16)acc[g * 8 + j];
    *(half8*)&op[g * 8] = o;
  }
}

extern "C" void kernel_launch(void* const* d_in, const int* in_sizes, int n_in,
                              void* d_out, int out_size, void* d_ws, size_t ws_size,
                              hipStream_t stream) {
  (void)in_sizes; (void)n_in; (void)out_size; (void)ws_size;
  const float* xq  = (const float*)d_in[0];
  const float* xkv = (const float*)d_in[1];
  const float* Wq  = (const float*)d_in[2];
  const float* Wk  = (const float*)d_in[3];
  const float* Wv  = (const float*)d_in[4];
  const float* Wo  = (const float*)d_in[5];

  char* ws = (char*)d_ws;
  _Float16* qp16 = (_Float16*)(ws + 0);           // [32768][1024]
  _Float16* kpT  = (_Float16*)(ws + 67108864);    // [4][1024][8192]
  _Float16* vT   = (_Float16*)(ws + 134217728);   // [4][1024][8192]
  _Float16* WqT  = (_Float16*)(ws + 201326592);
  _Float16* WkT  = (_Float16*)(ws + 203423744);
  _Float16* WvT  = (_Float16*)(ws + 205520896);
  _Float16* Wo16 = (_Float16*)(ws + 207618048);
  float*    ksum = (float*)(ws + 209715200);
  float*    kv   = (float*)(ws + 209731584);
  float*    kvpart = (float*)(ws + 210780160);
  _Float16* MT   = (_Float16*)(ws + 227557376);   // [4][1024][1024]

  _Float16* Xq16  = (_Float16*)d_out;
  _Float16* Xkv16 = Xq16 + 33554432;

  k_cvt<<<2048, 256, 0, stream>>>(xq,  Xq16,  8388608);
  k_cvt<<<2048, 256, 0, stream>>>(xkv, Xkv16, 8388608);
  k_cvt<<<512,  256, 0, stream>>>(Wo,  Wo16,  262144);
  k_cvt_t<<<3072, 256, 0, stream>>>(Wq, Wk, Wv, WqT, WkT, WvT);

  // projections: 256x256 tiles -> 128 x 4 = 512 blocks of 512 threads
  k_gemm<0, true ><<<512, 512, 0, stream>>>(Xq16,  WqT, qp16, 1.0f);
  k_gemm<1, true ><<<512, 512, 0, stream>>>(Xkv16, WkT, kpT,  1.0f);
  k_gemm<1, false><<<512, 512, 0, stream>>>(Xkv16, WvT, vT,   1.0f);

  k_ksum<<<1024, 256, 0, stream>>>(kpT, ksum);
  k_stageB<<<1024, 64, 0, stream>>>(kpT, vT, kvpart);
  k_reduce_kv<<<1024, 256, 0, stream>>>(kvpart, kv);

  k_zscale<<<8192, 256, 0, stream>>>(qp16, ksum);

  k_mker<<<256, 256, 0, stream>>>(kv, Wo16, MT);
  k_gemm<2, false><<<512, 512, 0, stream>>>(qp16, MT, d_out, 1.0f / ZSCALE);
}

// Round 10
// 502.559 us; speedup vs baseline: 1.0488x; 1.0266x over previous
//
#include <hip/hip_runtime.h>
#include <hip/hip_fp16.h>
#include <math.h>

typedef _Float16 half8  __attribute__((ext_vector_type(8)));
typedef _Float16 half4v __attribute__((ext_vector_type(4)));
typedef float    floatx4 __attribute__((ext_vector_type(4)));

#define NB   4
#define LL   8192
#define FF   1024
#define HH   16
#define DD   64
#define MTOT 32768
#define KK   1024
#define NN   1024
#define ZSCALE 65536.0f

__device__ __forceinline__ void gload_lds16(const void* g, void* l) {
  __builtin_amdgcn_global_load_lds(
      (const __attribute__((address_space(1))) void*)g,
      (__attribute__((address_space(3))) void*)l, 16, 0, 0);
}

__device__ __forceinline__ float phi_act(float x) {
  return x > 0.f ? x + 1.f : __expf(x);
}

// ---------- elementwise f32 -> f16 ----------
__global__ void k_cvt(const float* __restrict__ src, _Float16* __restrict__ dst, int n4) {
  int stride = gridDim.x * blockDim.x;
  for (int i = blockIdx.x * blockDim.x + threadIdx.x; i < n4; i += stride) {
    float4 v = reinterpret_cast<const float4*>(src)[i];
    half4v h;
    h[0] = (_Float16)v.x; h[1] = (_Float16)v.y; h[2] = (_Float16)v.z; h[3] = (_Float16)v.w;
    reinterpret_cast<half4v*>(dst)[i] = h;
  }
}

// ---------- transpose+convert three 1024x1024 weights: W[f][n] -> WT16[n][f] ----------
__global__ void k_cvt_t(const float* __restrict__ W0, const float* __restrict__ W1,
                        const float* __restrict__ W2,
                        _Float16* __restrict__ T0, _Float16* __restrict__ T1,
                        _Float16* __restrict__ T2) {
  __shared__ float tile[32][33];
  int bid = blockIdx.x;
  int w = bid >> 10, rem = bid & 1023;
  int ti = rem >> 5, tj = rem & 31;
  const float* src = (w == 0) ? W0 : (w == 1) ? W1 : W2;
  _Float16*    dst = (w == 0) ? T0 : (w == 1) ? T1 : T2;
  int t = threadIdx.x;
  int r = t >> 3, c4 = (t & 7) << 2;
  float4 v = *reinterpret_cast<const float4*>(&src[(size_t)(ti * 32 + r) * FF + tj * 32 + c4]);
  tile[r][c4 + 0] = v.x; tile[r][c4 + 1] = v.y; tile[r][c4 + 2] = v.z; tile[r][c4 + 3] = v.w;
  __syncthreads();
  half4v h;
  h[0] = (_Float16)tile[c4 + 0][r];
  h[1] = (_Float16)tile[c4 + 1][r];
  h[2] = (_Float16)tile[c4 + 2][r];
  h[3] = (_Float16)tile[c4 + 3][r];
  *reinterpret_cast<half4v*>(&dst[(size_t)(tj * 32 + r) * FF + ti * 32 + c4]) = h;
}

// ============ 256x256-tile quadrant-schedule GEMM (BK=64, 8 waves 2x4) ============
// Same structure as r7/r8; r9 changes:
//  (1) qmfma: dropped lgkmcnt(0)+sched_barrier(0) pin — all ds_reads are
//      compiler-emitted with tracked deps; every read is consumed by a
//      same-phase MFMA, so lgkm drains before each closing barrier anyway.
//  (2) MODE 1 fused K+V (N=2048 over stacked WkT|WvT): PHI + dest base by
//      wave-uniform column segment; deterministic ksum partial fold (seg 0).

template<int MATB, int HALF>
__device__ __forceinline__ void stage_half(const _Float16* __restrict__ G, int row0,
                                           int col0, _Float16* plane, int tid) {
  #pragma unroll
  for (int is = 0; is < 2; ++is) {
    int lin = is * 8192 + tid * 16;                 // linear dest byte in plane
    int swz = lin ^ (((lin >> 7) & 7) << 4);        // inverse-swizzled source
    int rp = swz >> 7;                              // plane row (= lin>>7)
    int kb = swz & 127;                             // swizzled k-byte
    int row;
    if constexpr (MATB) row = (rp >> 5) * 64 + HALF * 32 + (rp & 31);
    else                row = (rp >> 6) * 128 + HALF * 64 + (rp & 63);
    gload_lds16(G + (size_t)(row0 + row) * 1024 + col0 + (kb >> 1),
                (char*)plane + lin);
  }
}

__device__ __forceinline__ half8 frag_read(const _Float16* plane, int rp, int kk, int lh) {
  int byte = rp * 128 + kk * 64 + lh * 16;
  byte ^= ((byte >> 7) & 7) << 4;
  return *(const half8*)((const char*)plane + byte);
}

template<int MH, int NH>
__device__ __forceinline__ void qreads(const _Float16* sm, int buf,
                                       half8 (&bA)[8], half8 (&bB)[2][4],
                                       int wr, int wc, int lr, int lh) {
  if constexpr (NH == 0) {
    const _Float16* Ap = sm + buf * 32768 + MH * 8192;
    #pragma unroll
    for (int m = 0; m < 4; ++m)
      #pragma unroll
      for (int kk = 0; kk < 2; ++kk)
        bA[m * 2 + kk] = frag_read(Ap, wr * 64 + m * 16 + lr, kk, lh);
  }
  if constexpr (MH == 0) {
    const _Float16* Bp = sm + buf * 32768 + 16384 + NH * 8192;
    #pragma unroll
    for (int n = 0; n < 2; ++n)
      #pragma unroll
      for (int kk = 0; kk < 2; ++kk)
        bB[NH][n * 2 + kk] = frag_read(Bp, wc * 32 + n * 16 + lr, kk, lh);
  }
}

template<int MH, int NH, bool VM4>
__device__ __forceinline__ void qmfma(half8 (&bA)[8], half8 (&bB)[2][4],
                                      floatx4 (&acc)[8][4]) {
  if constexpr (VM4) {
    asm volatile("s_waitcnt vmcnt(4)" ::: "memory");
  }
  __builtin_amdgcn_s_barrier();
  __builtin_amdgcn_s_setprio(1);
  #pragma unroll
  for (int m = 0; m < 4; ++m)
    #pragma unroll
    for (int n = 0; n < 2; ++n)
      #pragma unroll
      for (int kk = 0; kk < 2; ++kk)
        acc[MH * 4 + m][NH * 2 + n] = __builtin_amdgcn_mfma_f32_16x16x32_f16(
            bA[m * 2 + kk], bB[NH][n * 2 + kk], acc[MH * 4 + m][NH * 2 + n], 0, 0, 0);
  __builtin_amdgcn_s_setprio(0);
  __builtin_amdgcn_s_barrier();
}

template<int TBUF>
__device__ __forceinline__ void do_tile(int t, const _Float16* __restrict__ Ab,
                                        const _Float16* __restrict__ Bb,
                                        int i0, int j0, _Float16* sm, int tid,
                                        half8 (&bA)[8], half8 (&bB)[2][4],
                                        floatx4 (&acc)[8][4],
                                        int wr, int wc, int lr, int lh) {
  _Float16* self  = sm + TBUF * 32768;
  _Float16* other = sm + (TBUF ^ 1) * 32768;
  const int c1 = ((t + 1 < 16) ? (t + 1) : 15) * 64;   // clamp: keep vmcnt counts uniform
  const int c2 = ((t + 2 < 16) ? (t + 2) : 15) * 64;
  // ph0 (MH0,NH0)
  qreads<0, 0>(sm, TBUF, bA, bB, wr, wc, lr, lh);
  stage_half<1, 1>(Bb, j0, c1, other + 24576, tid);    // t+1 B-h1
  qmfma<0, 0, false>(bA, bB, acc);
  // ph1 (MH0,NH1)
  qreads<0, 1>(sm, TBUF, bA, bB, wr, wc, lr, lh);
  stage_half<0, 1>(Ab, i0, c1, other + 8192, tid);     // t+1 A-h1
  qmfma<0, 1, false>(bA, bB, acc);
  // ph2 (MH1,NH0)
  qreads<1, 0>(sm, TBUF, bA, bB, wr, wc, lr, lh);
  stage_half<0, 0>(Ab, i0, c2, self + 0, tid);         // t+2 A-h0 (self buf; WAR-safe)
  qmfma<1, 0, false>(bA, bB, acc);
  // ph3 (MH1,NH1) — no reads
  stage_half<1, 0>(Bb, j0, c2, self + 16384, tid);     // t+2 B-h0 (self)
  qmfma<1, 1, true>(bA, bB, acc);                      // single vmcnt(4) per K-tile
}

// MODE 0: f16 C[row*1024+col] (opt PHI)
// MODE 1: fused K|V, N=2048: f16 transposed CT; seg=j0>>10 (0:K w/ phi+ksum, 1:V)
// MODE 2: f32 C*outScale, BT indexed per-batch
template<int MODE, bool PHI>
__global__ __launch_bounds__(512, 2)
void k_gemm(const _Float16* __restrict__ A, const _Float16* __restrict__ BT,
            void* __restrict__ Cptr, float* __restrict__ aux, float outScale) {
  __shared__ __align__(16) _Float16 smem[65536];   // 128 KiB
  const int tid  = threadIdx.x;
  const int lane = tid & 63;
  const int wid  = tid >> 6;
  const int wr = wid >> 2, wc = wid & 3;
  const int lr = lane & 15, lh = lane >> 4;

  // XCD-chunked block swizzle (bijective: ntiles % 8 == 0)
  constexpr int NT = (MODE == 1) ? 8 : 4;                    // N-tiles
  constexpr int CH = (MODE == 1) ? 128 : 64;                 // tiles per XCD chunk
  const int tile = (blockIdx.x & 7) * CH + (blockIdx.x >> 3);
  const int tm = tile / NT, tn = tile % NT;
  const int i0 = tm * 256, j0 = tn * 256;

  const _Float16* Ab = A;
  const _Float16* Bb = (MODE == 2) ? BT + ((size_t)(i0 >> 13)) * ((size_t)NN * KK) : BT;

  floatx4 acc[8][4];
  #pragma unroll
  for (int m = 0; m < 8; ++m)
    #pragma unroll
    for (int n = 0; n < 4; ++n)
      #pragma unroll
      for (int r = 0; r < 4; ++r) acc[m][n][r] = 0.f;

  _Float16* sm = (_Float16*)smem;
  half8 bA[8];
  half8 bB[2][4];

  // prologue: t0's 4 planes + t1's A-h0,B-h0 (6 stages = 12 loads); vmcnt(4)
  stage_half<0, 0>(Ab, i0, 0,  sm + 0,             tid);
  stage_half<1, 0>(Bb, j0, 0,  sm + 16384,         tid);
  stage_half<1, 1>(Bb, j0, 0,  sm + 24576,         tid);
  stage_half<0, 1>(Ab, i0, 0,  sm + 8192,          tid);
  stage_half<0, 0>(Ab, i0, 64, sm + 32768 + 0,     tid);
  stage_half<1, 0>(Bb, j0, 64, sm + 32768 + 16384, tid);
  asm volatile("s_waitcnt vmcnt(4)" ::: "memory");
  __builtin_amdgcn_s_barrier();

  #pragma unroll 1
  for (int tt = 0; tt < 8; ++tt) {
    do_tile<0>(2 * tt,     Ab, Bb, i0, j0, sm, tid, bA, bB, acc, wr, wc, lr, lh);
    do_tile<1>(2 * tt + 1, Ab, Bb, i0, j0, sm, tid, bA, bB, acc, wr, wc, lr, lh);
  }

  asm volatile("s_waitcnt vmcnt(0)" ::: "memory");
  __builtin_amdgcn_s_barrier();

  if constexpr (MODE == 0) {
    _Float16* C = (_Float16*)Cptr;
    #pragma unroll
    for (int m = 0; m < 8; ++m) {
      int row = i0 + wr * 128 + m * 16 + lh * 4;
      #pragma unroll
      for (int n = 0; n < 4; ++n) {
        int col = j0 + wc * 64 + n * 16 + lr;
        #pragma unroll
        for (int r = 0; r < 4; ++r) {
          float v = acc[m][n][r];
          if constexpr (PHI) v = phi_act(v);
          C[(size_t)(row + r) * NN + col] = (_Float16)v;
        }
      }
    }
  } else if constexpr (MODE == 2) {
    float* C = (float*)Cptr;
    #pragma unroll
    for (int m = 0; m < 8; ++m) {
      int row = i0 + wr * 128 + m * 16 + lh * 4;
      #pragma unroll
      for (int n = 0; n < 4; ++n) {
        int col = j0 + wc * 64 + n * 16 + lr;
        #pragma unroll
        for (int r = 0; r < 4; ++r)
          C[(size_t)(row + r) * NN + col] = acc[m][n][r] * outScale;
      }
    }
  } else {
    // fused K|V transposed store via LDS (smem = 256n x 256l f16 = 128KB)
    const int seg = j0 >> 10;            // 0 = K (phi + ksum fold), 1 = V
    const int j0s = j0 & 1023;
    const int bb  = i0 >> 13;
    const int l0  = i0 & 8191;
    float s[4] = {0.f, 0.f, 0.f, 0.f};
    #pragma unroll
    for (int m = 0; m < 8; ++m) {
      int l0l = wr * 128 + m * 16 + lh * 4;
      #pragma unroll
      for (int n = 0; n < 4; ++n) {
        int n_loc = wc * 64 + n * 16 + lr;
        int byte = (n_loc * 512 + l0l * 2) ^ ((n_loc & 7) << 4);
        half4v h;
        #pragma unroll
        for (int r = 0; r < 4; ++r) {
          float v = acc[m][n][r];
          if (seg == 0) { v = phi_act(v); s[n] += v; }
          h[r] = (_Float16)v;
        }
        *(half4v*)((char*)sm + byte) = h;
      }
    }
    if (seg == 0) {
      // deterministic ksum partials: reduce over lh groups (same col, rows differ)
      #pragma unroll
      for (int n = 0; n < 4; ++n) {
        s[n] += __shfl_xor(s[n], 16);
        s[n] += __shfl_xor(s[n], 32);
      }
      if (lh == 0) {
        int ch = (l0 >> 7) + wr;                     // 64 chunks of 128 l-rows
        size_t base = ((size_t)bb * 64 + ch) * 1024 + j0s + wc * 64 + lr;
        #pragma unroll
        for (int n = 0; n < 4; ++n) aux[base + n * 16] = s[n];
      }
    }
    __syncthreads();
    _Float16* C = (_Float16*)Cptr;                   // = kpT; vT = kpT + 4*1024*LL
    const size_t nbase = ((size_t)seg * 4 + bb) * 1024 + j0s;
    #pragma unroll 1
    for (int pass = 0; pass < 16; ++pass) {
      int n_loc = pass * 16 + (tid >> 5);
      int lo = (tid & 31) * 16;                      // byte offset within 512B l-row
      int byte = (n_loc * 512 + lo) ^ ((n_loc & 7) << 4);
      half8 v = *(const half8*)((char*)sm + byte);
      *(half8*)&C[(nbase + n_loc) * LL + l0 + (lo >> 1)] = v;
    }
  }
}

// ---------- reduce ksum partials: ksum[b][col] = sum_64 part[b][ch][col] ----------
__global__ void k_ksum_red(const float* __restrict__ part, float* __restrict__ ksum) {
  int i = blockIdx.x * 256 + threadIdx.x;     // 4096
  int b = i >> 10, col = i & 1023;
  float s = 0.f;
  for (int c = 0; c < 64; ++c) s += part[((size_t)b * 64 + c) * 1024 + col];
  ksum[i] = s;
}

// ---------- kv partials: per (b,h,chunk) wave computes 64x64 = kp^T(chunk) * v(chunk) ----------
__global__ __launch_bounds__(64)
void k_stageB(const _Float16* __restrict__ kpT, const _Float16* __restrict__ vT,
              float* __restrict__ kvpart) {
  __shared__ _Float16 Ak[64 * 72];
  __shared__ _Float16 Bv[64 * 72];
  const int bid = blockIdx.x;
  const int bh = bid >> 4, cc = bid & 15;
  const int lane = threadIdx.x;
  const int lr = lane & 15, lh = lane >> 4;
  const _Float16* Ab = kpT + (size_t)bh * 64 * LL + cc * 512;
  const _Float16* Bb = vT  + (size_t)bh * 64 * LL + cc * 512;

  floatx4 acc[4][4];
  #pragma unroll
  for (int m = 0; m < 4; ++m)
    #pragma unroll
    for (int n = 0; n < 4; ++n)
      #pragma unroll
      for (int r = 0; r < 4; ++r) acc[m][n][r] = 0.f;

  for (int kt = 0; kt < 512; kt += 64) {
    __syncthreads();
    #pragma unroll
    for (int j = 0; j < 8; ++j) {
      int chunk = lane + 64 * j;
      int rr = chunk >> 3;
      int off = (chunk & 7) * 8;
      *(half8*)&Ak[rr * 72 + off] = *(const half8*)&Ab[(size_t)rr * LL + kt + off];
      *(half8*)&Bv[rr * 72 + off] = *(const half8*)&Bb[(size_t)rr * LL + kt + off];
    }
    __syncthreads();
    #pragma unroll
    for (int ks = 0; ks < 2; ++ks) {
      half8 af[4], bf[4];
      #pragma unroll
      for (int m = 0; m < 4; ++m) af[m] = *(const half8*)&Ak[(m * 16 + lr) * 72 + ks * 32 + lh * 8];
      #pragma unroll
      for (int n = 0; n < 4; ++n) bf[n] = *(const half8*)&Bv[(n * 16 + lr) * 72 + ks * 32 + lh * 8];
      #pragma unroll
      for (int m = 0; m < 4; ++m)
        #pragma unroll
        for (int n = 0; n < 4; ++n)
          acc[m][n] = __builtin_amdgcn_mfma_f32_16x16x32_f16(af[m], bf[n], acc[m][n], 0, 0, 0);
    }
  }
  float* op = kvpart + (size_t)bid * 4096;
  #pragma unroll
  for (int m = 0; m < 4; ++m)
    #pragma unroll
    for (int n = 0; n < 4; ++n)
      #pragma unroll
      for (int r = 0; r < 4; ++r)
        op[(m * 16 + lh * 4 + r) * 64 + n * 16 + lr] = acc[m][n][r];
}

// ---------- reduce kv partials over 16 chunks ----------
__global__ void k_reduce_kv(const float* __restrict__ kvpart, float* __restrict__ kv) {
  int gid = blockIdx.x * 256 + threadIdx.x;
  int bh = gid >> 12, i = gid & 4095;
  float s = 0.f;
  for (int c = 0; c < 16; ++c) s += kvpart[((size_t)bh * 16 + c) * 4096 + i];
  kv[gid] = s;
}

// ---------- z = ZSCALE / (phi(q).ksum_h + eps) per head; qp *= z in place ----------
__global__ void k_zscale(_Float16* __restrict__ qp, const float* __restrict__ ksum) {
  int w = threadIdx.x >> 6, lane = threadIdx.x & 63;
  int row = blockIdx.x * 4 + w;
  int b = row >> 13;
  int h = lane >> 2;
  _Float16* p = qp + (size_t)row * 1024 + lane * 16;
  half8 v0 = *(half8*)&p[0];
  half8 v1 = *(half8*)&p[8];
  const float* ks = ksum + ((size_t)b * 16 + h) * 64 + (lane & 3) * 16;
  float dot = 0.f;
  #pragma unroll
  for (int e = 0; e < 8; ++e) dot += (float)v0[e] * ks[e];
  #pragma unroll
  for (int e = 0; e < 8; ++e) dot += (float)v1[e] * ks[8 + e];
  dot += __shfl_xor(dot, 1);
  dot += __shfl_xor(dot, 2);
  float zf = ZSCALE / (dot + 1e-6f);
  #pragma unroll
  for (int e = 0; e < 8; ++e) v0[e] = (_Float16)((float)v0[e] * zf);
  #pragma unroll
  for (int e = 0; e < 8; ++e) v1[e] = (_Float16)((float)v1[e] * zf);
  *(half8*)&p[0] = v0;
  *(half8*)&p[8] = v1;
}

// ---------- MT[b][f][h*64+d] = sum_e kv[b,h,d,e] * Wo[h,e,f] ----------
__global__ __launch_bounds__(256)
void k_mker(const float* __restrict__ kv, const _Float16* __restrict__ Wo16,
            _Float16* __restrict__ MT) {
  __shared__ float kvs[4096];
  int bid = blockIdx.x;
  int fc = bid & 3, h = (bid >> 2) & 15, b = bid >> 6;
  const float* kvp = kv + ((size_t)b * 16 + h) * 4096;
  for (int i = threadIdx.x; i < 4096; i += 256) kvs[i] = kvp[i];
  __syncthreads();
  int f = fc * 256 + threadIdx.x;
  float acc[64];
  #pragma unroll
  for (int d = 0; d < 64; ++d) acc[d] = 0.f;
  for (int e = 0; e < 64; ++e) {
    float wv = (float)Wo16[(size_t)(h * 64 + e) * 1024 + f];
    #pragma unroll
    for (int d = 0; d < 64; ++d) acc[d] = fmaf(kvs[d * 64 + e], wv, acc[d]);
  }
  _Float16* op = MT + ((size_t)b * 1024 + f) * 1024 + h * 64;
  #pragma unroll
  for (int g = 0; g < 8; ++g) {
    half8 o;
    #pragma unroll
    for (int j = 0; j < 8; ++j) o[j] = (_Float16)acc[g * 8 + j];
    *(half8*)&op[g * 8] = o;
  }
}

extern "C" void kernel_launch(void* const* d_in, const int* in_sizes, int n_in,
                              void* d_out, int out_size, void* d_ws, size_t ws_size,
                              hipStream_t stream) {
  (void)in_sizes; (void)n_in; (void)out_size; (void)ws_size;
  const float* xq  = (const float*)d_in[0];
  const float* xkv = (const float*)d_in[1];
  const float* Wq  = (const float*)d_in[2];
  const float* Wk  = (const float*)d_in[3];
  const float* Wv  = (const float*)d_in[4];
  const float* Wo  = (const float*)d_in[5];

  char* ws = (char*)d_ws;
  _Float16* qp16 = (_Float16*)(ws + 0);           // [32768][1024]
  _Float16* kpT  = (_Float16*)(ws + 67108864);    // [4][1024][8192]
  _Float16* vT   = (_Float16*)(ws + 134217728);   // [4][1024][8192] (= kpT + 4*1024*LL)
  _Float16* WqT  = (_Float16*)(ws + 201326592);
  _Float16* WkT  = (_Float16*)(ws + 203423744);   // [WkT|WvT] contiguous 2048x1024
  _Float16* WvT  = (_Float16*)(ws + 205520896);
  _Float16* Wo16 = (_Float16*)(ws + 207618048);
  float*    ksum = (float*)(ws + 209715200);      // [4][1024]
  float*    kv   = (float*)(ws + 209731584);      // [4][16][64][64]
  float*    kvpart = (float*)(ws + 210780160);    // 16MB (k_stageB partials)
  float*    ksum_part = (float*)(ws + 210780160); // 1MB [4][64][1024] — time-disjoint w/ kvpart
  _Float16* MT   = (_Float16*)(ws + 227557376);   // [4][1024][1024]

  _Float16* Xq16  = (_Float16*)d_out;
  _Float16* Xkv16 = Xq16 + 33554432;

  k_cvt<<<2048, 256, 0, stream>>>(xq,  Xq16,  8388608);
  k_cvt<<<2048, 256, 0, stream>>>(xkv, Xkv16, 8388608);
  k_cvt<<<512,  256, 0, stream>>>(Wo,  Wo16,  262144);
  k_cvt_t<<<3072, 256, 0, stream>>>(Wq, Wk, Wv, WqT, WkT, WvT);

  // Q projection (512 blocks) + fused K|V projection (1024 blocks, N=2048)
  k_gemm<0, true ><<<512,  512, 0, stream>>>(Xq16,  WqT, qp16, nullptr,   1.0f);
  k_gemm<1, false><<<1024, 512, 0, stream>>>(Xkv16, WkT, kpT,  ksum_part, 1.0f);

  k_ksum_red<<<16, 256, 0, stream>>>(ksum_part, ksum);
  k_stageB<<<1024, 64, 0, stream>>>(kpT, vT, kvpart);
  k_reduce_kv<<<1024, 256, 0, stream>>>(kvpart, kv);

  k_zscale<<<8192, 256, 0, stream>>>(qp16, ksum);

  k_mker<<<256, 256, 0, stream>>>(kv, Wo16, MT);
  k_gemm<2, false><<<512, 512, 0, stream>>>(qp16, MT, d_out, nullptr, 1.0f / ZSCALE);
}

// Round 11
// 462.624 us; speedup vs baseline: 1.1394x; 1.0863x over previous
//
#include <hip/hip_runtime.h>
#include <hip/hip_fp16.h>
#include <math.h>

typedef _Float16 half8  __attribute__((ext_vector_type(8)));
typedef _Float16 half4v __attribute__((ext_vector_type(4)));
typedef float    floatx4 __attribute__((ext_vector_type(4)));

#define NB   4
#define LL   8192
#define FF   1024
#define HH   16
#define DD   64
#define MTOT 32768
#define KK   1024
#define NN   1024
#define ZSCALE 65536.0f

__device__ __forceinline__ void gload_lds16(const void* g, void* l) {
  __builtin_amdgcn_global_load_lds(
      (const __attribute__((address_space(1))) void*)g,
      (__attribute__((address_space(3))) void*)l, 16, 0, 0);
}

__device__ __forceinline__ float phi_act(float x) {
  return x > 0.f ? x + 1.f : __expf(x);
}

// ---------- fused elementwise f32 -> f16 for two arrays ----------
__global__ void k_cvt2(const float* __restrict__ a, const float* __restrict__ b,
                       _Float16* __restrict__ da, _Float16* __restrict__ db, int n4each) {
  int stride = gridDim.x * blockDim.x;
  for (int i = blockIdx.x * blockDim.x + threadIdx.x; i < 2 * n4each; i += stride) {
    const float* s; _Float16* d; int j;
    if (i < n4each) { s = a; d = da; j = i; }
    else            { s = b; d = db; j = i - n4each; }
    float4 v = reinterpret_cast<const float4*>(s)[j];
    half4v h;
    h[0] = (_Float16)v.x; h[1] = (_Float16)v.y; h[2] = (_Float16)v.z; h[3] = (_Float16)v.w;
    reinterpret_cast<half4v*>(d)[j] = h;
  }
}

// ---------- elementwise f32 -> f16 ----------
__global__ void k_cvt(const float* __restrict__ src, _Float16* __restrict__ dst, int n4) {
  int stride = gridDim.x * blockDim.x;
  for (int i = blockIdx.x * blockDim.x + threadIdx.x; i < n4; i += stride) {
    float4 v = reinterpret_cast<const float4*>(src)[i];
    half4v h;
    h[0] = (_Float16)v.x; h[1] = (_Float16)v.y; h[2] = (_Float16)v.z; h[3] = (_Float16)v.w;
    reinterpret_cast<half4v*>(dst)[i] = h;
  }
}

// ---------- transpose+convert three 1024x1024 weights: W[f][n] -> WT16[n][f] ----------
__global__ void k_cvt_t(const float* __restrict__ W0, const float* __restrict__ W1,
                        const float* __restrict__ W2,
                        _Float16* __restrict__ T0, _Float16* __restrict__ T1,
                        _Float16* __restrict__ T2) {
  __shared__ float tile[32][33];
  int bid = blockIdx.x;
  int w = bid >> 10, rem = bid & 1023;
  int ti = rem >> 5, tj = rem & 31;
  const float* src = (w == 0) ? W0 : (w == 1) ? W1 : W2;
  _Float16*    dst = (w == 0) ? T0 : (w == 1) ? T1 : T2;
  int t = threadIdx.x;
  int r = t >> 3, c4 = (t & 7) << 2;
  float4 v = *reinterpret_cast<const float4*>(&src[(size_t)(ti * 32 + r) * FF + tj * 32 + c4]);
  tile[r][c4 + 0] = v.x; tile[r][c4 + 1] = v.y; tile[r][c4 + 2] = v.z; tile[r][c4 + 3] = v.w;
  __syncthreads();
  half4v h;
  h[0] = (_Float16)tile[c4 + 0][r];
  h[1] = (_Float16)tile[c4 + 1][r];
  h[2] = (_Float16)tile[c4 + 2][r];
  h[3] = (_Float16)tile[c4 + 3][r];
  *reinterpret_cast<half4v*>(&dst[(size_t)(tj * 32 + r) * FF + ti * 32 + c4]) = h;
}

// ============ 256x256-tile quadrant-schedule GEMM (BK=64, 8 waves 2x4) ============
// r11: MODE 0 epilogue now folds the z-normalizer (phi + per-head dot with ksum
// + scale) — k_zscale pass deleted.  Otherwise identical to r9/r10.

template<int MATB, int HALF>
__device__ __forceinline__ void stage_half(const _Float16* __restrict__ G, int row0,
                                           int col0, _Float16* plane, int tid) {
  #pragma unroll
  for (int is = 0; is < 2; ++is) {
    int lin = is * 8192 + tid * 16;                 // linear dest byte in plane
    int swz = lin ^ (((lin >> 7) & 7) << 4);        // inverse-swizzled source
    int rp = swz >> 7;                              // plane row (= lin>>7)
    int kb = swz & 127;                             // swizzled k-byte
    int row;
    if constexpr (MATB) row = (rp >> 5) * 64 + HALF * 32 + (rp & 31);
    else                row = (rp >> 6) * 128 + HALF * 64 + (rp & 63);
    gload_lds16(G + (size_t)(row0 + row) * 1024 + col0 + (kb >> 1),
                (char*)plane + lin);
  }
}

__device__ __forceinline__ half8 frag_read(const _Float16* plane, int rp, int kk, int lh) {
  int byte = rp * 128 + kk * 64 + lh * 16;
  byte ^= ((byte >> 7) & 7) << 4;
  return *(const half8*)((const char*)plane + byte);
}

template<int MH, int NH>
__device__ __forceinline__ void qreads(const _Float16* sm, int buf,
                                       half8 (&bA)[8], half8 (&bB)[2][4],
                                       int wr, int wc, int lr, int lh) {
  if constexpr (NH == 0) {
    const _Float16* Ap = sm + buf * 32768 + MH * 8192;
    #pragma unroll
    for (int m = 0; m < 4; ++m)
      #pragma unroll
      for (int kk = 0; kk < 2; ++kk)
        bA[m * 2 + kk] = frag_read(Ap, wr * 64 + m * 16 + lr, kk, lh);
  }
  if constexpr (MH == 0) {
    const _Float16* Bp = sm + buf * 32768 + 16384 + NH * 8192;
    #pragma unroll
    for (int n = 0; n < 2; ++n)
      #pragma unroll
      for (int kk = 0; kk < 2; ++kk)
        bB[NH][n * 2 + kk] = frag_read(Bp, wc * 32 + n * 16 + lr, kk, lh);
  }
}

template<int MH, int NH, bool VM4>
__device__ __forceinline__ void qmfma(half8 (&bA)[8], half8 (&bB)[2][4],
                                      floatx4 (&acc)[8][4]) {
  if constexpr (VM4) {
    asm volatile("s_waitcnt vmcnt(4)" ::: "memory");
  }
  __builtin_amdgcn_s_barrier();
  __builtin_amdgcn_s_setprio(1);
  #pragma unroll
  for (int m = 0; m < 4; ++m)
    #pragma unroll
    for (int n = 0; n < 2; ++n)
      #pragma unroll
      for (int kk = 0; kk < 2; ++kk)
        acc[MH * 4 + m][NH * 2 + n] = __builtin_amdgcn_mfma_f32_16x16x32_f16(
            bA[m * 2 + kk], bB[NH][n * 2 + kk], acc[MH * 4 + m][NH * 2 + n], 0, 0, 0);
  __builtin_amdgcn_s_setprio(0);
  __builtin_amdgcn_s_barrier();
}

template<int TBUF>
__device__ __forceinline__ void do_tile(int t, const _Float16* __restrict__ Ab,
                                        const _Float16* __restrict__ Bb,
                                        int i0, int j0, _Float16* sm, int tid,
                                        half8 (&bA)[8], half8 (&bB)[2][4],
                                        floatx4 (&acc)[8][4],
                                        int wr, int wc, int lr, int lh) {
  _Float16* self  = sm + TBUF * 32768;
  _Float16* other = sm + (TBUF ^ 1) * 32768;
  const int c1 = ((t + 1 < 16) ? (t + 1) : 15) * 64;   // clamp: keep vmcnt counts uniform
  const int c2 = ((t + 2 < 16) ? (t + 2) : 15) * 64;
  // ph0 (MH0,NH0)
  qreads<0, 0>(sm, TBUF, bA, bB, wr, wc, lr, lh);
  stage_half<1, 1>(Bb, j0, c1, other + 24576, tid);    // t+1 B-h1
  qmfma<0, 0, false>(bA, bB, acc);
  // ph1 (MH0,NH1)
  qreads<0, 1>(sm, TBUF, bA, bB, wr, wc, lr, lh);
  stage_half<0, 1>(Ab, i0, c1, other + 8192, tid);     // t+1 A-h1
  qmfma<0, 1, false>(bA, bB, acc);
  // ph2 (MH1,NH0)
  qreads<1, 0>(sm, TBUF, bA, bB, wr, wc, lr, lh);
  stage_half<0, 0>(Ab, i0, c2, self + 0, tid);         // t+2 A-h0 (self buf; WAR-safe)
  qmfma<1, 0, false>(bA, bB, acc);
  // ph3 (MH1,NH1) — no reads
  stage_half<1, 0>(Bb, j0, c2, self + 16384, tid);     // t+2 B-h0 (self)
  qmfma<1, 1, true>(bA, bB, acc);                      // single vmcnt(4) per K-tile
}

// MODE 0: Q-proj: phi + z-fold (aux = ksum, read) -> f16 qp
// MODE 1: fused K|V, N=2048: f16 transposed CT; seg=j0>>10 (0:K w/ phi+ksum part, 1:V)
// MODE 2: f32 C*outScale, BT indexed per-batch
template<int MODE, bool PHI>
__global__ __launch_bounds__(512, 2)
void k_gemm(const _Float16* __restrict__ A, const _Float16* __restrict__ BT,
            void* __restrict__ Cptr, float* __restrict__ aux, float outScale) {
  __shared__ __align__(16) _Float16 smem[65536];   // 128 KiB
  const int tid  = threadIdx.x;
  const int lane = tid & 63;
  const int wid  = tid >> 6;
  const int wr = wid >> 2, wc = wid & 3;
  const int lr = lane & 15, lh = lane >> 4;

  // XCD-chunked block swizzle (bijective: ntiles % 8 == 0)
  constexpr int NT = (MODE == 1) ? 8 : 4;                    // N-tiles
  constexpr int CH = (MODE == 1) ? 128 : 64;                 // tiles per XCD chunk
  const int tile = (blockIdx.x & 7) * CH + (blockIdx.x >> 3);
  const int tm = tile / NT, tn = tile % NT;
  const int i0 = tm * 256, j0 = tn * 256;

  const _Float16* Ab = A;
  const _Float16* Bb = (MODE == 2) ? BT + ((size_t)(i0 >> 13)) * ((size_t)NN * KK) : BT;

  floatx4 acc[8][4];
  #pragma unroll
  for (int m = 0; m < 8; ++m)
    #pragma unroll
    for (int n = 0; n < 4; ++n)
      #pragma unroll
      for (int r = 0; r < 4; ++r) acc[m][n][r] = 0.f;

  _Float16* sm = (_Float16*)smem;
  half8 bA[8];
  half8 bB[2][4];

  // prologue: t0's 4 planes + t1's A-h0,B-h0 (6 stages = 12 loads); vmcnt(4)
  stage_half<0, 0>(Ab, i0, 0,  sm + 0,             tid);
  stage_half<1, 0>(Bb, j0, 0,  sm + 16384,         tid);
  stage_half<1, 1>(Bb, j0, 0,  sm + 24576,         tid);
  stage_half<0, 1>(Ab, i0, 0,  sm + 8192,          tid);
  stage_half<0, 0>(Ab, i0, 64, sm + 32768 + 0,     tid);
  stage_half<1, 0>(Bb, j0, 64, sm + 32768 + 16384, tid);
  asm volatile("s_waitcnt vmcnt(4)" ::: "memory");
  __builtin_amdgcn_s_barrier();

  #pragma unroll 1
  for (int tt = 0; tt < 8; ++tt) {
    do_tile<0>(2 * tt,     Ab, Bb, i0, j0, sm, tid, bA, bB, acc, wr, wc, lr, lh);
    do_tile<1>(2 * tt + 1, Ab, Bb, i0, j0, sm, tid, bA, bB, acc, wr, wc, lr, lh);
  }

  asm volatile("s_waitcnt vmcnt(0)" ::: "memory");
  __builtin_amdgcn_s_barrier();

  if constexpr (MODE == 0) {
    // z-fold epilogue: p = phi(acc); dot = sum_d p*ksum over this head's 64 cols
    // (cols live in this wave: 16 lanes (lr) x 4 n); zf = ZSCALE/(dot+eps).
    _Float16* C = (_Float16*)Cptr;
    const int bq = i0 >> 13;
    float ks[4];
    #pragma unroll
    for (int n = 0; n < 4; ++n)
      ks[n] = aux[(size_t)bq * 1024 + j0 + wc * 64 + n * 16 + lr];
    #pragma unroll
    for (int m = 0; m < 8; ++m) {
      int row = i0 + wr * 128 + m * 16 + lh * 4;
      #pragma unroll
      for (int r = 0; r < 4; ++r) {
        float p[4];
        float dot = 0.f;
        #pragma unroll
        for (int n = 0; n < 4; ++n) {
          p[n] = phi_act(acc[m][n][r]);
          dot = fmaf(p[n], ks[n], dot);
        }
        dot += __shfl_xor(dot, 1);
        dot += __shfl_xor(dot, 2);
        dot += __shfl_xor(dot, 4);
        dot += __shfl_xor(dot, 8);
        float zf = ZSCALE / (dot + 1e-6f);
        #pragma unroll
        for (int n = 0; n < 4; ++n)
          C[(size_t)(row + r) * NN + j0 + wc * 64 + n * 16 + lr] = (_Float16)(p[n] * zf);
      }
    }
  } else if constexpr (MODE == 2) {
    float* C = (float*)Cptr;
    #pragma unroll
    for (int m = 0; m < 8; ++m) {
      int row = i0 + wr * 128 + m * 16 + lh * 4;
      #pragma unroll
      for (int n = 0; n < 4; ++n) {
        int col = j0 + wc * 64 + n * 16 + lr;
        #pragma unroll
        for (int r = 0; r < 4; ++r)
          C[(size_t)(row + r) * NN + col] = acc[m][n][r] * outScale;
      }
    }
  } else {
    // fused K|V transposed store via LDS (smem = 256n x 256l f16 = 128KB)
    const int seg = j0 >> 10;            // 0 = K (phi + ksum fold), 1 = V
    const int j0s = j0 & 1023;
    const int bb  = i0 >> 13;
    const int l0  = i0 & 8191;
    float s[4] = {0.f, 0.f, 0.f, 0.f};
    #pragma unroll
    for (int m = 0; m < 8; ++m) {
      int l0l = wr * 128 + m * 16 + lh * 4;
      #pragma unroll
      for (int n = 0; n < 4; ++n) {
        int n_loc = wc * 64 + n * 16 + lr;
        int byte = (n_loc * 512 + l0l * 2) ^ ((n_loc & 7) << 4);
        half4v h;
        #pragma unroll
        for (int r = 0; r < 4; ++r) {
          float v = acc[m][n][r];
          if (seg == 0) { v = phi_act(v); s[n] += v; }
          h[r] = (_Float16)v;
        }
        *(half4v*)((char*)sm + byte) = h;
      }
    }
    if (seg == 0) {
      // deterministic ksum partials: reduce over lh groups (same col, rows differ)
      #pragma unroll
      for (int n = 0; n < 4; ++n) {
        s[n] += __shfl_xor(s[n], 16);
        s[n] += __shfl_xor(s[n], 32);
      }
      if (lh == 0) {
        int ch = (l0 >> 7) + wr;                     // 64 chunks of 128 l-rows
        size_t base = ((size_t)bb * 64 + ch) * 1024 + j0s + wc * 64 + lr;
        #pragma unroll
        for (int n = 0; n < 4; ++n) aux[base + n * 16] = s[n];
      }
    }
    __syncthreads();
    _Float16* C = (_Float16*)Cptr;                   // = kpT; vT = kpT + 4*1024*LL
    const size_t nbase = ((size_t)seg * 4 + bb) * 1024 + j0s;
    #pragma unroll 1
    for (int pass = 0; pass < 16; ++pass) {
      int n_loc = pass * 16 + (tid >> 5);
      int lo = (tid & 31) * 16;                      // byte offset within 512B l-row
      int byte = (n_loc * 512 + lo) ^ ((n_loc & 7) << 4);
      half8 v = *(const half8*)((char*)sm + byte);
      *(half8*)&C[(nbase + n_loc) * LL + l0 + (lo >> 1)] = v;
    }
  }
}

// ---------- reduce ksum partials: ksum[b][col] = sum_64 part[b][ch][col] ----------
__global__ void k_ksum_red(const float* __restrict__ part, float* __restrict__ ksum) {
  int i = blockIdx.x * 256 + threadIdx.x;     // 4096
  int b = i >> 10, col = i & 1023;
  float s = 0.f;
  for (int c = 0; c < 64; ++c) s += part[((size_t)b * 64 + c) * 1024 + col];
  ksum[i] = s;
}

// ---------- kv partials: per (b,h,chunk) wave computes 64x64 = kp^T(chunk) * v(chunk) ----------
__global__ __launch_bounds__(64)
void k_stageB(const _Float16* __restrict__ kpT, const _Float16* __restrict__ vT,
              float* __restrict__ kvpart) {
  __shared__ _Float16 Ak[64 * 72];
  __shared__ _Float16 Bv[64 * 72];
  const int bid = blockIdx.x;
  const int bh = bid >> 4, cc = bid & 15;
  const int lane = threadIdx.x;
  const int lr = lane & 15, lh = lane >> 4;
  const _Float16* Ab = kpT + (size_t)bh * 64 * LL + cc * 512;
  const _Float16* Bb = vT  + (size_t)bh * 64 * LL + cc * 512;

  floatx4 acc[4][4];
  #pragma unroll
  for (int m = 0; m < 4; ++m)
    #pragma unroll
    for (int n = 0; n < 4; ++n)
      #pragma unroll
      for (int r = 0; r < 4; ++r) acc[m][n][r] = 0.f;

  for (int kt = 0; kt < 512; kt += 64) {
    __syncthreads();
    #pragma unroll
    for (int j = 0; j < 8; ++j) {
      int chunk = lane + 64 * j;
      int rr = chunk >> 3;
      int off = (chunk & 7) * 8;
      *(half8*)&Ak[rr * 72 + off] = *(const half8*)&Ab[(size_t)rr * LL + kt + off];
      *(half8*)&Bv[rr * 72 + off] = *(const half8*)&Bb[(size_t)rr * LL + kt + off];
    }
    __syncthreads();
    #pragma unroll
    for (int ks = 0; ks < 2; ++ks) {
      half8 af[4], bf[4];
      #pragma unroll
      for (int m = 0; m < 4; ++m) af[m] = *(const half8*)&Ak[(m * 16 + lr) * 72 + ks * 32 + lh * 8];
      #pragma unroll
      for (int n = 0; n < 4; ++n) bf[n] = *(const half8*)&Bv[(n * 16 + lr) * 72 + ks * 32 + lh * 8];
      #pragma unroll
      for (int m = 0; m < 4; ++m)
        #pragma unroll
        for (int n = 0; n < 4; ++n)
          acc[m][n] = __builtin_amdgcn_mfma_f32_16x16x32_f16(af[m], bf[n], acc[m][n], 0, 0, 0);
    }
  }
  float* op = kvpart + (size_t)bid * 4096;
  #pragma unroll
  for (int m = 0; m < 4; ++m)
    #pragma unroll
    for (int n = 0; n < 4; ++n)
      #pragma unroll
      for (int r = 0; r < 4; ++r)
        op[(m * 16 + lh * 4 + r) * 64 + n * 16 + lr] = acc[m][n][r];
}

// ---------- reduce kv partials over 16 chunks ----------
__global__ void k_reduce_kv(const float* __restrict__ kvpart, float* __restrict__ kv) {
  int gid = blockIdx.x * 256 + threadIdx.x;
  int bh = gid >> 12, i = gid & 4095;
  float s = 0.f;
  for (int c = 0; c < 16; ++c) s += kvpart[((size_t)bh * 16 + c) * 4096 + i];
  kv[gid] = s;
}

// ---------- MT[b][f][h*64+d] = sum_e kv[b,h,d,e] * Wo[h,e,f] ----------
__global__ __launch_bounds__(256)
void k_mker(const float* __restrict__ kv, const _Float16* __restrict__ Wo16,
            _Float16* __restrict__ MT) {
  __shared__ float kvs[4096];
  int bid = blockIdx.x;
  int fc = bid & 3, h = (bid >> 2) & 15, b = bid >> 6;
  const float* kvp = kv + ((size_t)b * 16 + h) * 4096;
  for (int i = threadIdx.x; i < 4096; i += 256) kvs[i] = kvp[i];
  __syncthreads();
  int f = fc * 256 + threadIdx.x;
  float acc[64];
  #pragma unroll
  for (int d = 0; d < 64; ++d) acc[d] = 0.f;
  for (int e = 0; e < 64; ++e) {
    float wv = (float)Wo16[(size_t)(h * 64 + e) * 1024 + f];
    #pragma unroll
    for (int d = 0; d < 64; ++d) acc[d] = fmaf(kvs[d * 64 + e], wv, acc[d]);
  }
  _Float16* op = MT + ((size_t)b * 1024 + f) * 1024 + h * 64;
  #pragma unroll
  for (int g = 0; g < 8; ++g) {
    half8 o;
    #pragma unroll
    for (int j = 0; j < 8; ++j) o[j] = (_Float16)acc[g * 8 + j];
    *(half8*)&op[g * 8] = o;
  }
}

extern "C" void kernel_launch(void* const* d_in, const int* in_sizes, int n_in,
                              void* d_out, int out_size, void* d_ws, size_t ws_size,
                              hipStream_t stream) {
  (void)in_sizes; (void)n_in; (void)out_size; (void)ws_size;
  const float* xq  = (const float*)d_in[0];
  const float* xkv = (const float*)d_in[1];
  const float* Wq  = (const float*)d_in[2];
  const float* Wk  = (const float*)d_in[3];
  const float* Wv  = (const float*)d_in[4];
  const float* Wo  = (const float*)d_in[5];

  char* ws = (char*)d_ws;
  _Float16* qp16 = (_Float16*)(ws + 0);           // [32768][1024]
  _Float16* kpT  = (_Float16*)(ws + 67108864);    // [4][1024][8192]
  _Float16* vT   = (_Float16*)(ws + 134217728);   // [4][1024][8192] (= kpT + 4*1024*LL)
  _Float16* WqT  = (_Float16*)(ws + 201326592);
  _Float16* WkT  = (_Float16*)(ws + 203423744);   // [WkT|WvT] contiguous 2048x1024
  _Float16* WvT  = (_Float16*)(ws + 205520896);
  _Float16* Wo16 = (_Float16*)(ws + 207618048);
  float*    ksum = (float*)(ws + 209715200);      // [4][1024]
  float*    kv   = (float*)(ws + 209731584);      // [4][16][64][64]
  float*    kvpart = (float*)(ws + 210780160);    // 16MB (k_stageB partials)
  float*    ksum_part = (float*)(ws + 210780160); // 1MB [4][64][1024] — read BEFORE stageB overwrites
  _Float16* MT   = (_Float16*)(ws + 227557376);   // [4][1024][1024]

  _Float16* Xq16  = (_Float16*)d_out;
  _Float16* Xkv16 = Xq16 + 33554432;

  // input + weight conversion
  k_cvt2<<<4096, 256, 0, stream>>>(xq, xkv, Xq16, Xkv16, 8388608);
  k_cvt<<<512,  256, 0, stream>>>(Wo, Wo16, 262144);
  k_cvt_t<<<3072, 256, 0, stream>>>(Wq, Wk, Wv, WqT, WkT, WvT);

  // fused K|V projection (writes kpT, vT, ksum partials)
  k_gemm<1, false><<<1024, 512, 0, stream>>>(Xkv16, WkT, kpT, ksum_part, 1.0f);
  k_ksum_red<<<16, 256, 0, stream>>>(ksum_part, ksum);

  // kv state + output-projection matrix
  k_stageB<<<1024, 64, 0, stream>>>(kpT, vT, kvpart);
  k_reduce_kv<<<1024, 256, 0, stream>>>(kvpart, kv);
  k_mker<<<256, 256, 0, stream>>>(kv, Wo16, MT);

  // Q projection with fused phi + z scaling (reads ksum)
  k_gemm<0, true><<<512, 512, 0, stream>>>(Xq16, WqT, qp16, ksum, 1.0f);

  // final GEMM -> d_out (f32), undo 2^16 scale
  k_gemm<2, false><<<512, 512, 0, stream>>>(qp16, MT, d_out, nullptr, 1.0f / ZSCALE);
}

// Round 12
// 429.827 us; speedup vs baseline: 1.2263x; 1.0763x over previous
//
#include <hip/hip_runtime.h>
#include <hip/hip_fp16.h>
#include <math.h>

typedef _Float16 half8  __attribute__((ext_vector_type(8)));
typedef _Float16 half4v __attribute__((ext_vector_type(4)));
typedef float    floatx4 __attribute__((ext_vector_type(4)));

#define NB   4
#define LL   8192
#define FF   1024
#define HH   16
#define DD   64
#define MTOT 32768
#define KK   1024
#define NN   1024
#define ZSCALE 65536.0f

__device__ __forceinline__ void gload_lds16(const void* g, void* l) {
  __builtin_amdgcn_global_load_lds(
      (const __attribute__((address_space(1))) void*)g,
      (__attribute__((address_space(3))) void*)l, 16, 0, 0);
}

__device__ __forceinline__ float phi_act(float x) {
  return x > 0.f ? x + 1.f : __expf(x);
}

// ---------- fused elementwise f32 -> f16 for two arrays ----------
__global__ void k_cvt2(const float* __restrict__ a, const float* __restrict__ b,
                       _Float16* __restrict__ da, _Float16* __restrict__ db, int n4each) {
  int stride = gridDim.x * blockDim.x;
  for (int i = blockIdx.x * blockDim.x + threadIdx.x; i < 2 * n4each; i += stride) {
    const float* s; _Float16* d; int j;
    if (i < n4each) { s = a; d = da; j = i; }
    else            { s = b; d = db; j = i - n4each; }
    float4 v = reinterpret_cast<const float4*>(s)[j];
    half4v h;
    h[0] = (_Float16)v.x; h[1] = (_Float16)v.y; h[2] = (_Float16)v.z; h[3] = (_Float16)v.w;
    reinterpret_cast<half4v*>(d)[j] = h;
  }
}

// ---------- elementwise f32 -> f16 ----------
__global__ void k_cvt(const float* __restrict__ src, _Float16* __restrict__ dst, int n4) {
  int stride = gridDim.x * blockDim.x;
  for (int i = blockIdx.x * blockDim.x + threadIdx.x; i < n4; i += stride) {
    float4 v = reinterpret_cast<const float4*>(src)[i];
    half4v h;
    h[0] = (_Float16)v.x; h[1] = (_Float16)v.y; h[2] = (_Float16)v.z; h[3] = (_Float16)v.w;
    reinterpret_cast<half4v*>(dst)[i] = h;
  }
}

// ---------- transpose+convert weights ----------
// Wq -> T0 [1024][1024]; Wk,Wv -> TKV [2048][1024] interleaved per head:
//   head h rows h*128..h*128+63 = WkT(h), rows h*128+64..+127 = WvT(h).
__global__ void k_cvt_t(const float* __restrict__ W0, const float* __restrict__ W1,
                        const float* __restrict__ W2,
                        _Float16* __restrict__ T0, _Float16* __restrict__ TKV) {
  __shared__ float tile[32][33];
  int bid = blockIdx.x;
  int w = bid >> 10, rem = bid & 1023;
  int ti = rem >> 5, tj = rem & 31;
  const float* src = (w == 0) ? W0 : (w == 1) ? W1 : W2;
  int t = threadIdx.x;
  int r = t >> 3, c4 = (t & 7) << 2;
  float4 v = *reinterpret_cast<const float4*>(&src[(size_t)(ti * 32 + r) * FF + tj * 32 + c4]);
  tile[r][c4 + 0] = v.x; tile[r][c4 + 1] = v.y; tile[r][c4 + 2] = v.z; tile[r][c4 + 3] = v.w;
  __syncthreads();
  half4v h;
  h[0] = (_Float16)tile[c4 + 0][r];
  h[1] = (_Float16)tile[c4 + 1][r];
  h[2] = (_Float16)tile[c4 + 2][r];
  h[3] = (_Float16)tile[c4 + 3][r];
  int n = tj * 32 + r;
  _Float16* dst; size_t orow;
  if (w == 0) { dst = T0;  orow = n; }
  else        { dst = TKV; orow = (size_t)(n >> 6) * 128 + (n & 63) + (w == 2 ? 64 : 0); }
  *reinterpret_cast<half4v*>(&dst[orow * FF + ti * 32 + c4]) = h;
}

// ============ 256x256-tile quadrant-schedule GEMM (BK=64, 8 waves 2x4) ============
// r12: MODE 1 no longer materializes kpT/vT.  Epilogue: LDS transpose (as
// before) -> in-block kv partials via MFMA over l (K=256) -> 32MB f32 partials.
// Weight layout for MODE 1 is head-interleaved [K(h)|V(h)] so each 256-col
// tile holds 2 complete heads.  k_stageB deleted.

template<int MATB, int HALF>
__device__ __forceinline__ void stage_half(const _Float16* __restrict__ G, int row0,
                                           int col0, _Float16* plane, int tid) {
  #pragma unroll
  for (int is = 0; is < 2; ++is) {
    int lin = is * 8192 + tid * 16;                 // linear dest byte in plane
    int swz = lin ^ (((lin >> 7) & 7) << 4);        // inverse-swizzled source
    int rp = swz >> 7;                              // plane row (= lin>>7)
    int kb = swz & 127;                             // swizzled k-byte
    int row;
    if constexpr (MATB) row = (rp >> 5) * 64 + HALF * 32 + (rp & 31);
    else                row = (rp >> 6) * 128 + HALF * 64 + (rp & 63);
    gload_lds16(G + (size_t)(row0 + row) * 1024 + col0 + (kb >> 1),
                (char*)plane + lin);
  }
}

__device__ __forceinline__ half8 frag_read(const _Float16* plane, int rp, int kk, int lh) {
  int byte = rp * 128 + kk * 64 + lh * 16;
  byte ^= ((byte >> 7) & 7) << 4;
  return *(const half8*)((const char*)plane + byte);
}

template<int MH, int NH>
__device__ __forceinline__ void qreads(const _Float16* sm, int buf,
                                       half8 (&bA)[8], half8 (&bB)[2][4],
                                       int wr, int wc, int lr, int lh) {
  if constexpr (NH == 0) {
    const _Float16* Ap = sm + buf * 32768 + MH * 8192;
    #pragma unroll
    for (int m = 0; m < 4; ++m)
      #pragma unroll
      for (int kk = 0; kk < 2; ++kk)
        bA[m * 2 + kk] = frag_read(Ap, wr * 64 + m * 16 + lr, kk, lh);
  }
  if constexpr (MH == 0) {
    const _Float16* Bp = sm + buf * 32768 + 16384 + NH * 8192;
    #pragma unroll
    for (int n = 0; n < 2; ++n)
      #pragma unroll
      for (int kk = 0; kk < 2; ++kk)
        bB[NH][n * 2 + kk] = frag_read(Bp, wc * 32 + n * 16 + lr, kk, lh);
  }
}

template<int MH, int NH, bool VM4>
__device__ __forceinline__ void qmfma(half8 (&bA)[8], half8 (&bB)[2][4],
                                      floatx4 (&acc)[8][4]) {
  if constexpr (VM4) {
    asm volatile("s_waitcnt vmcnt(4)" ::: "memory");
  }
  __builtin_amdgcn_s_barrier();
  __builtin_amdgcn_s_setprio(1);
  #pragma unroll
  for (int m = 0; m < 4; ++m)
    #pragma unroll
    for (int n = 0; n < 2; ++n)
      #pragma unroll
      for (int kk = 0; kk < 2; ++kk)
        acc[MH * 4 + m][NH * 2 + n] = __builtin_amdgcn_mfma_f32_16x16x32_f16(
            bA[m * 2 + kk], bB[NH][n * 2 + kk], acc[MH * 4 + m][NH * 2 + n], 0, 0, 0);
  __builtin_amdgcn_s_setprio(0);
  __builtin_amdgcn_s_barrier();
}

template<int TBUF>
__device__ __forceinline__ void do_tile(int t, const _Float16* __restrict__ Ab,
                                        const _Float16* __restrict__ Bb,
                                        int i0, int j0, _Float16* sm, int tid,
                                        half8 (&bA)[8], half8 (&bB)[2][4],
                                        floatx4 (&acc)[8][4],
                                        int wr, int wc, int lr, int lh) {
  _Float16* self  = sm + TBUF * 32768;
  _Float16* other = sm + (TBUF ^ 1) * 32768;
  const int c1 = ((t + 1 < 16) ? (t + 1) : 15) * 64;   // clamp: keep vmcnt counts uniform
  const int c2 = ((t + 2 < 16) ? (t + 2) : 15) * 64;
  // ph0 (MH0,NH0)
  qreads<0, 0>(sm, TBUF, bA, bB, wr, wc, lr, lh);
  stage_half<1, 1>(Bb, j0, c1, other + 24576, tid);    // t+1 B-h1
  qmfma<0, 0, false>(bA, bB, acc);
  // ph1 (MH0,NH1)
  qreads<0, 1>(sm, TBUF, bA, bB, wr, wc, lr, lh);
  stage_half<0, 1>(Ab, i0, c1, other + 8192, tid);     // t+1 A-h1
  qmfma<0, 1, false>(bA, bB, acc);
  // ph2 (MH1,NH0)
  qreads<1, 0>(sm, TBUF, bA, bB, wr, wc, lr, lh);
  stage_half<0, 0>(Ab, i0, c2, self + 0, tid);         // t+2 A-h0 (self buf; WAR-safe)
  qmfma<1, 0, false>(bA, bB, acc);
  // ph3 (MH1,NH1) — no reads
  stage_half<1, 0>(Bb, j0, c2, self + 16384, tid);     // t+2 B-h0 (self)
  qmfma<1, 1, true>(bA, bB, acc);                      // single vmcnt(4) per K-tile
}

// MODE 0: Q-proj: phi + z-fold (aux = ksum, read) -> f16 qp
// MODE 1: fused K|V proj (interleaved heads): aux = ksum partials (write),
//         aux2 = kv partials (write).  No C output.
// MODE 2: f32 C*outScale, BT indexed per-batch
template<int MODE, bool PHI>
__global__ __launch_bounds__(512, 2)
void k_gemm(const _Float16* __restrict__ A, const _Float16* __restrict__ BT,
            void* __restrict__ Cptr, float* __restrict__ aux, float* __restrict__ aux2,
            float outScale) {
  __shared__ __align__(16) _Float16 smem[65536];   // 128 KiB
  const int tid  = threadIdx.x;
  const int lane = tid & 63;
  const int wid  = tid >> 6;
  const int wr = wid >> 2, wc = wid & 3;
  const int lr = lane & 15, lh = lane >> 4;

  // XCD-chunked block swizzle (bijective: ntiles % 8 == 0)
  constexpr int NT = (MODE == 1) ? 8 : 4;                    // N-tiles
  constexpr int CH = (MODE == 1) ? 128 : 64;                 // tiles per XCD chunk
  const int tile = (blockIdx.x & 7) * CH + (blockIdx.x >> 3);
  const int tm = tile / NT, tn = tile % NT;
  const int i0 = tm * 256, j0 = tn * 256;

  const _Float16* Ab = A;
  const _Float16* Bb = (MODE == 2) ? BT + ((size_t)(i0 >> 13)) * ((size_t)NN * KK) : BT;

  floatx4 acc[8][4];
  #pragma unroll
  for (int m = 0; m < 8; ++m)
    #pragma unroll
    for (int n = 0; n < 4; ++n)
      #pragma unroll
      for (int r = 0; r < 4; ++r) acc[m][n][r] = 0.f;

  _Float16* sm = (_Float16*)smem;
  half8 bA[8];
  half8 bB[2][4];

  // prologue: t0's 4 planes + t1's A-h0,B-h0 (6 stages = 12 loads); vmcnt(4)
  stage_half<0, 0>(Ab, i0, 0,  sm + 0,             tid);
  stage_half<1, 0>(Bb, j0, 0,  sm + 16384,         tid);
  stage_half<1, 1>(Bb, j0, 0,  sm + 24576,         tid);
  stage_half<0, 1>(Ab, i0, 0,  sm + 8192,          tid);
  stage_half<0, 0>(Ab, i0, 64, sm + 32768 + 0,     tid);
  stage_half<1, 0>(Bb, j0, 64, sm + 32768 + 16384, tid);
  asm volatile("s_waitcnt vmcnt(4)" ::: "memory");
  __builtin_amdgcn_s_barrier();

  #pragma unroll 1
  for (int tt = 0; tt < 8; ++tt) {
    do_tile<0>(2 * tt,     Ab, Bb, i0, j0, sm, tid, bA, bB, acc, wr, wc, lr, lh);
    do_tile<1>(2 * tt + 1, Ab, Bb, i0, j0, sm, tid, bA, bB, acc, wr, wc, lr, lh);
  }

  asm volatile("s_waitcnt vmcnt(0)" ::: "memory");
  __builtin_amdgcn_s_barrier();

  if constexpr (MODE == 0) {
    // z-fold epilogue: p = phi(acc); dot = sum_d p*ksum over this head's 64 cols
    _Float16* C = (_Float16*)Cptr;
    const int bq = i0 >> 13;
    float ks[4];
    #pragma unroll
    for (int n = 0; n < 4; ++n)
      ks[n] = aux[(size_t)bq * 1024 + j0 + wc * 64 + n * 16 + lr];
    #pragma unroll
    for (int m = 0; m < 8; ++m) {
      int row = i0 + wr * 128 + m * 16 + lh * 4;
      #pragma unroll
      for (int r = 0; r < 4; ++r) {
        float p[4];
        float dot = 0.f;
        #pragma unroll
        for (int n = 0; n < 4; ++n) {
          p[n] = phi_act(acc[m][n][r]);
          dot = fmaf(p[n], ks[n], dot);
        }
        dot += __shfl_xor(dot, 1);
        dot += __shfl_xor(dot, 2);
        dot += __shfl_xor(dot, 4);
        dot += __shfl_xor(dot, 8);
        float zf = ZSCALE / (dot + 1e-6f);
        #pragma unroll
        for (int n = 0; n < 4; ++n)
          C[(size_t)(row + r) * NN + j0 + wc * 64 + n * 16 + lr] = (_Float16)(p[n] * zf);
      }
    }
  } else if constexpr (MODE == 2) {
    float* C = (float*)Cptr;
    #pragma unroll
    for (int m = 0; m < 8; ++m) {
      int row = i0 + wr * 128 + m * 16 + lh * 4;
      #pragma unroll
      for (int n = 0; n < 4; ++n) {
        int col = j0 + wc * 64 + n * 16 + lr;
        #pragma unroll
        for (int r = 0; r < 4; ++r)
          C[(size_t)(row + r) * NN + col] = acc[m][n][r] * outScale;
      }
    }
  } else {
    // fused K|V epilogue: tile cols = [K(h0)|V(h0)|K(h1)|V(h1)], h0 = 2tn.
    // 1) LDS transpose store (swizzled) with phi on K cols + ksum partials;
    // 2) in-block kv partials: kv[d][e] += phiK[l,d]*V[l,e] via MFMA (K=256).
    const int b  = i0 >> 13;
    const int l0 = i0 & 8191;
    const int isK = !(wc & 1);                 // wave-uniform: wc 0,2 = K cols
    const int hh  = tn * 2 + (wc >> 1);        // this wave's head (global)
    float s[4] = {0.f, 0.f, 0.f, 0.f};
    #pragma unroll
    for (int m = 0; m < 8; ++m) {
      int l0l = wr * 128 + m * 16 + lh * 4;
      #pragma unroll
      for (int n = 0; n < 4; ++n) {
        int n_loc = wc * 64 + n * 16 + lr;
        int byte = (n_loc * 512 + l0l * 2) ^ ((n_loc & 7) << 4);
        half4v h;
        #pragma unroll
        for (int r = 0; r < 4; ++r) {
          float v = acc[m][n][r];
          if (isK) { v = phi_act(v); s[n] += v; }
          h[r] = (_Float16)v;
        }
        *(half4v*)((char*)sm + byte) = h;
      }
    }
    if (isK) {
      #pragma unroll
      for (int n = 0; n < 4; ++n) {
        s[n] += __shfl_xor(s[n], 16);
        s[n] += __shfl_xor(s[n], 32);
      }
      if (lh == 0) {
        int ch = (l0 >> 7) + wr;                     // 64 chunks of 128 l-rows per b
        size_t base = ((size_t)b * 64 + ch) * 1024 + (size_t)hh * 64 + lr;
        #pragma unroll
        for (int n = 0; n < 4; ++n) aux[base + n * 16] = s[n];
      }
    }
    __syncthreads();
    // kv partials: wave w -> head (w>>2), d-block ((w>>1)&1)*32, e-block (w&1)*32
    const int khd = wid >> 2;
    const int db = ((wid >> 1) & 1) * 32, eb = (wid & 1) * 32;
    const int hb = khd * 128;                        // tile-local head base (n_loc)
    floatx4 a2[2][2];
    #pragma unroll
    for (int md = 0; md < 2; ++md)
      #pragma unroll
      for (int ne = 0; ne < 2; ++ne)
        #pragma unroll
        for (int r = 0; r < 4; ++r) a2[md][ne][r] = 0.f;
    #pragma unroll 1
    for (int ks2 = 0; ks2 < 8; ++ks2) {
      half8 af[2], bf[2];
      #pragma unroll
      for (int md = 0; md < 2; ++md) {
        int n_loc = hb + db + md * 16 + lr;          // phiK^T row (d over l)
        int byte = (n_loc * 512 + ks2 * 64 + lh * 16) ^ ((n_loc & 7) << 4);
        af[md] = *(const half8*)((const char*)sm + byte);
      }
      #pragma unroll
      for (int ne = 0; ne < 2; ++ne) {
        int n_loc = hb + 64 + eb + ne * 16 + lr;     // V^T row (e over l)
        int byte = (n_loc * 512 + ks2 * 64 + lh * 16) ^ ((n_loc & 7) << 4);
        bf[ne] = *(const half8*)((const char*)sm + byte);
      }
      #pragma unroll
      for (int md = 0; md < 2; ++md)
        #pragma unroll
        for (int ne = 0; ne < 2; ++ne)
          a2[md][ne] = __builtin_amdgcn_mfma_f32_16x16x32_f16(af[md], bf[ne], a2[md][ne], 0, 0, 0);
    }
    const int lch = l0 >> 8;                         // 32 chunks of 256 l-rows per b
    float* op = aux2 + ((((size_t)b * 16 + tn * 2 + khd) * 32) + lch) * 4096;
    #pragma unroll
    for (int md = 0; md < 2; ++md)
      #pragma unroll
      for (int ne = 0; ne < 2; ++ne)
        #pragma unroll
        for (int r = 0; r < 4; ++r)
          op[(db + md * 16 + lh * 4 + r) * 64 + eb + ne * 16 + lr] = a2[md][ne][r];
  }
}

// ---------- reduce ksum partials: ksum[b][col] = sum_64 part[b][ch][col] ----------
__global__ void k_ksum_red(const float* __restrict__ part, float* __restrict__ ksum) {
  int i = blockIdx.x * 256 + threadIdx.x;     // 4096
  int b = i >> 10, col = i & 1023;
  float s = 0.f;
  for (int c = 0; c < 64; ++c) s += part[((size_t)b * 64 + c) * 1024 + col];
  ksum[i] = s;
}

// ---------- reduce kv partials over 32 chunks ----------
__global__ void k_reduce_kv(const float* __restrict__ kvpart, float* __restrict__ kv) {
  int gid = blockIdx.x * 256 + threadIdx.x;   // 262144
  int bh = gid >> 12, i = gid & 4095;
  float s = 0.f;
  for (int c = 0; c < 32; ++c) s += kvpart[((size_t)bh * 32 + c) * 4096 + i];
  kv[gid] = s;
}

// ---------- MT[b][f][h*64+d] = sum_e kv[b,h,d,e] * Wo[h,e,f] ----------
__global__ __launch_bounds__(256)
void k_mker(const float* __restrict__ kv, const _Float16* __restrict__ Wo16,
            _Float16* __restrict__ MT) {
  __shared__ float kvs[4096];
  int bid = blockIdx.x;
  int fc = bid & 3, h = (bid >> 2) & 15, b = bid >> 6;
  const float* kvp = kv + ((size_t)b * 16 + h) * 4096;
  for (int i = threadIdx.x; i < 4096; i += 256) kvs[i] = kvp[i];
  __syncthreads();
  int f = fc * 256 + threadIdx.x;
  float acc[64];
  #pragma unroll
  for (int d = 0; d < 64; ++d) acc[d] = 0.f;
  for (int e = 0; e < 64; ++e) {
    float wv = (float)Wo16[(size_t)(h * 64 + e) * 1024 + f];
    #pragma unroll
    for (int d = 0; d < 64; ++d) acc[d] = fmaf(kvs[d * 64 + e], wv, acc[d]);
  }
  _Float16* op = MT + ((size_t)b * 1024 + f) * 1024 + h * 64;
  #pragma unroll
  for (int g = 0; g < 8; ++g) {
    half8 o;
    #pragma unroll
    for (int j = 0; j < 8; ++j) o[j] = (_Float16)acc[g * 8 + j];
    *(half8*)&op[g * 8] = o;
  }
}

extern "C" void kernel_launch(void* const* d_in, const int* in_sizes, int n_in,
                              void* d_out, int out_size, void* d_ws, size_t ws_size,
                              hipStream_t stream) {
  (void)in_sizes; (void)n_in; (void)out_size; (void)ws_size;
  const float* xq  = (const float*)d_in[0];
  const float* xkv = (const float*)d_in[1];
  const float* Wq  = (const float*)d_in[2];
  const float* Wk  = (const float*)d_in[3];
  const float* Wv  = (const float*)d_in[4];
  const float* Wo  = (const float*)d_in[5];

  char* ws = (char*)d_ws;
  _Float16* qp16   = (_Float16*)(ws + 0);          // 64MB [32768][1024]
  float*    kvpart = (float*)(ws + 67108864);      // 32MB [4][16][32][4096]
  float*    ksum_part = (float*)(ws + 100663296);  // 1MB  [4][64][1024]
  float*    ksum   = (float*)(ws + 101711872);     // 16KB [4][1024]
  float*    kv     = (float*)(ws + 101728256);     // 1MB  [4][16][64][64]
  _Float16* WqT    = (_Float16*)(ws + 102776832);  // 2MB
  _Float16* WKV    = (_Float16*)(ws + 104873984);  // 4MB  [2048][1024] head-interleaved
  _Float16* Wo16   = (_Float16*)(ws + 109068288);  // 2MB
  _Float16* MT     = (_Float16*)(ws + 111165440);  // 8MB  [4][1024][1024]

  _Float16* Xq16  = (_Float16*)d_out;
  _Float16* Xkv16 = Xq16 + 33554432;

  // input + weight conversion
  k_cvt2<<<4096, 256, 0, stream>>>(xq, xkv, Xq16, Xkv16, 8388608);
  k_cvt<<<512,  256, 0, stream>>>(Wo, Wo16, 262144);
  k_cvt_t<<<3072, 256, 0, stream>>>(Wq, Wk, Wv, WqT, WKV);

  // fused K|V projection -> ksum partials + kv partials (no kpT/vT materialization)
  k_gemm<1, false><<<1024, 512, 0, stream>>>(Xkv16, WKV, nullptr, ksum_part, kvpart, 1.0f);
  k_ksum_red<<<16, 256, 0, stream>>>(ksum_part, ksum);
  k_reduce_kv<<<1024, 256, 0, stream>>>(kvpart, kv);
  k_mker<<<256, 256, 0, stream>>>(kv, Wo16, MT);

  // Q projection with fused phi + z scaling (reads ksum)
  k_gemm<0, true><<<512, 512, 0, stream>>>(Xq16, WqT, qp16, ksum, nullptr, 1.0f);

  // final GEMM -> d_out (f32), undo 2^16 scale
  k_gemm<2, false><<<512, 512, 0, stream>>>(qp16, MT, d_out, nullptr, nullptr, 1.0f / ZSCALE);
}